// Round 8
// baseline (314.259 us; speedup 1.0000x reference)
//
#include <hip/hip_runtime.h>
#include <math.h>

#define N_NODES 8192
#define N_EDGES 131072
#define C 32
#define Zn 10
#define NG 16
#define NB 8
#define H 64
#define TABN 4096
#define PPB 32     // table points per block
#define XS 73      // table activation LDS stride
#define NPB 8      // nodes per node_kernel block

__device__ __forceinline__ float silu_f(float v){ return v / (1.0f + __expf(-v)); }

// ================================================================ prep (fused):
// blocks [0,512): rcv histogram (r-filtered)
// blocks [512,544): species + full h0 row init (includes zero padding)
// blocks [544,802): radial MLP tables (both iterations, interleaved lerp pairs)
__global__ __launch_bounds__(256)
void prep_kernel(const float* __restrict__ pos, const int* __restrict__ ei,
                 int* __restrict__ counts,
                 const float* __restrict__ na, const float* __restrict__ Wemb,
                 int* __restrict__ species, float* __restrict__ hg,
                 const float* __restrict__ R0g, const float* __restrict__ R1g,
                 const float* __restrict__ R2g, const float* __restrict__ R3g,
                 float2* __restrict__ Tab2){
  __shared__ float xsh[PPB*XS];
  int b = blockIdx.x;
  int tid = threadIdx.x;

  if (b < 512){
    int e = b*256 + tid;
    int snd = ei[e], rcv = ei[N_EDGES + e];
    float px = pos[rcv*3+0]-pos[snd*3+0];
    float py = pos[rcv*3+1]-pos[snd*3+1];
    float pz = pos[rcv*3+2]-pos[snd*3+2];
    float r2 = px*px+py*py+pz*pz;
    if (r2 < 25.0f) atomicAdd(counts + rcv, 1);
    return;
  }
  if (b < 544){
    int n = (b-512)*256 + tid;
    int spec = 0;
    #pragma unroll
    for (int z = 1; z < Zn; z++) if (na[n*Zn+z] > 0.5f) spec = z;
    species[n] = spec;
    float4* hrow = (float4*)(hg + (size_t)n*288);
    const float4* wrow = (const float4*)(Wemb + spec*C);
    #pragma unroll
    for (int q = 0; q < 8; q++) hrow[q] = wrow[q];
    float4 z4 = make_float4(0.f,0.f,0.f,0.f);
    #pragma unroll
    for (int q = 8; q < 72; q++) hrow[q] = z4;
    return;
  }

  // ---- table part
  int tb = b - 544;
  const int nb = (TABN + PPB)/PPB;   // 129
  int half = tb / nb;
  int blk  = tb - half*nb;
  const float* R0i = R0g + half*NB*H;
  const float* R1i = R1g + half*H*H;
  const float* R2i = R2g + half*H*H;
  const float* R3i = R3g + half*H*96;
  float2* TabH = Tab2 + (size_t)half*((size_t)TABN*96);

  int pl = tid >> 3, jt = tid & 7;
  int i = blk*PPB + pl;
  float r = (i == 0) ? 1e-6f : (float)i * (5.0f/TABN);
  {
    float xr = r*0.2f;
    float env = 0.f;
    if (xr < 1.0f){
      float x2 = xr*xr, x5 = x2*x2*xr;
      env = 1.f - 21.f*x5 + 35.f*x5*xr - 15.f*x5*x2;
    }
    float sc = 0.6324555320336759f / r * env;
    xsh[pl*XS + jt] = sc * sinf((float)(jt+1)*0.6283185307179586f*r);
  }
  __syncthreads();

  float acc[12];
  #pragma unroll
  for (int j = 0; j < 8; j++) acc[j] = 0.f;
  #pragma unroll
  for (int k = 0; k < 8; k++){
    float xk = xsh[pl*XS + k];
    const float4* w4 = (const float4*)(R0i + k*H + jt*8);
    float4 wa = w4[0], wb = w4[1];
    acc[0]=fmaf(xk,wa.x,acc[0]); acc[1]=fmaf(xk,wa.y,acc[1]);
    acc[2]=fmaf(xk,wa.z,acc[2]); acc[3]=fmaf(xk,wa.w,acc[3]);
    acc[4]=fmaf(xk,wb.x,acc[4]); acc[5]=fmaf(xk,wb.y,acc[5]);
    acc[6]=fmaf(xk,wb.z,acc[6]); acc[7]=fmaf(xk,wb.w,acc[7]);
  }
  __syncthreads();
  #pragma unroll
  for (int j = 0; j < 8; j++) xsh[pl*XS + jt*8 + j] = silu_f(acc[j]);
  __syncthreads();

  const float* Wl[2] = {R1i, R2i};
  #pragma unroll
  for (int L = 0; L < 2; L++){
    const float* W = Wl[L];
    #pragma unroll
    for (int j = 0; j < 8; j++) acc[j] = 0.f;
    for (int k = 0; k < H; k++){
      float xk = xsh[pl*XS + k];
      const float4* w4 = (const float4*)(W + k*H + jt*8);
      float4 wa = w4[0], wb = w4[1];
      acc[0]=fmaf(xk,wa.x,acc[0]); acc[1]=fmaf(xk,wa.y,acc[1]);
      acc[2]=fmaf(xk,wa.z,acc[2]); acc[3]=fmaf(xk,wa.w,acc[3]);
      acc[4]=fmaf(xk,wb.x,acc[4]); acc[5]=fmaf(xk,wb.y,acc[5]);
      acc[6]=fmaf(xk,wb.z,acc[6]); acc[7]=fmaf(xk,wb.w,acc[7]);
    }
    __syncthreads();
    #pragma unroll
    for (int j = 0; j < 8; j++) xsh[pl*XS + jt*8 + j] = silu_f(acc[j]);
    __syncthreads();
  }

  #pragma unroll
  for (int j = 0; j < 12; j++) acc[j] = 0.f;
  for (int k = 0; k < H; k++){
    float xk = xsh[pl*XS + k];
    const float4* w4 = (const float4*)(R3i + k*96 + jt*12);
    float4 wa = w4[0], wb = w4[1], wc = w4[2];
    acc[0]=fmaf(xk,wa.x,acc[0]);  acc[1]=fmaf(xk,wa.y,acc[1]);
    acc[2]=fmaf(xk,wa.z,acc[2]);  acc[3]=fmaf(xk,wa.w,acc[3]);
    acc[4]=fmaf(xk,wb.x,acc[4]);  acc[5]=fmaf(xk,wb.y,acc[5]);
    acc[6]=fmaf(xk,wb.z,acc[6]);  acc[7]=fmaf(xk,wb.w,acc[7]);
    acc[8]=fmaf(xk,wc.x,acc[8]);  acc[9]=fmaf(xk,wc.y,acc[9]);
    acc[10]=fmaf(xk,wc.z,acc[10]); acc[11]=fmaf(xk,wc.w,acc[11]);
  }
  if (i <= TABN){
    int cb = jt*12;
    #pragma unroll
    for (int j = 0; j < 12; j++){
      int c = cb + j;
      float val = acc[j];
      if (i < TABN) TabH[(size_t)i*96 + c].x = val;      // lerp lower endpoint
      if (i > 0)    TabH[(size_t)(i-1)*96 + c].y = val;  // lerp upper endpoint
    }
  }
}

// ================================================================ scan
__global__ __launch_bounds__(256)
void scan_kernel(const int* __restrict__ counts, int* __restrict__ row_start,
                 int* __restrict__ cursor){
  __shared__ int part[256];
  int tid = threadIdx.x;
  int local[32];
  int s = 0;
  const int4* c4 = (const int4*)counts;
  #pragma unroll
  for (int i8 = 0; i8 < 8; i8++){
    int4 v = c4[tid*8 + i8];
    local[i8*4+0] = s; s += v.x;
    local[i8*4+1] = s; s += v.y;
    local[i8*4+2] = s; s += v.z;
    local[i8*4+3] = s; s += v.w;
  }
  part[tid] = s; __syncthreads();
  for (int off = 1; off < 256; off <<= 1){
    int v = (tid >= off) ? part[tid-off] : 0;
    __syncthreads();
    part[tid] += v;
    __syncthreads();
  }
  int excl = part[tid] - s;
  int base = tid*32;
  #pragma unroll
  for (int i = 0; i < 32; i++){
    int v = excl + local[i];
    row_start[base+i] = v;
    cursor[base+i] = v;
  }
  if (tid == 255) row_start[N_NODES] = part[255];
}

// ================================================================ fill CSR slots + inline Y (geometry recomputed, pos is L1/L2-hot)
__global__ __launch_bounds__(256)
void fill_geom_kernel(const float* __restrict__ pos, const int* __restrict__ ei,
                      int* __restrict__ cursor, float* __restrict__ Ye,
                      float2* __restrict__ rsp){
  int e = blockIdx.x*256 + threadIdx.x;
  int snd = ei[e], rcv = ei[N_EDGES + e];
  float px = pos[rcv*3+0]-pos[snd*3+0];
  float py = pos[rcv*3+1]-pos[snd*3+1];
  float pz = pos[rcv*3+2]-pos[snd*3+2];
  float r = sqrtf(px*px+py*py+pz*pz + 1e-12f);
  if (r < 5.0f){
    int p = atomicAdd(cursor + rcv, 1);
    float inv = 1.0f/r;
    float x = px*inv, y = py*inv, z = pz*inv;
    const float s3 = 1.7320508075688772f;
    const float s5 = 2.23606797749979f;
    const float s15 = 3.872983346207417f;
    float* ye = Ye + (size_t)p*16;
    *(float4*)(ye)   = make_float4(1.f, s3*x, s3*y, s3*z);
    *(float4*)(ye+4) = make_float4(s15*x*y, s15*y*z, 0.5f*s5*(3.f*z*z-1.f), s15*x*z);
    ye[8] = 0.5f*s15*(x*x-y*y);
    rsp[p] = make_float2(r, __int_as_float(snd));
  }
}

// ================================================================ mix helper: one slot job across all NPB nodes
// acc[n2] += sum_q src[n2*288 + m*32+q] * Wg[l(m)*1024 + q*32 + c31]
__device__ __forceinline__ void mix_job(const float* __restrict__ Wg,
                                        const float* __restrict__ src,
                                        int m, int c31, float* accv){
  int l = (m >= 4) ? 2 : ((m >= 1) ? 1 : 0);
  const float* wbase = Wg + l*1024 + c31;
  const float* sbase = src + m*32;
  #pragma unroll
  for (int qc = 0; qc < 8; qc++){
    float w0 = wbase[(4*qc+0)*32];
    float w1 = wbase[(4*qc+1)*32];
    float w2 = wbase[(4*qc+2)*32];
    float w3 = wbase[(4*qc+3)*32];
    #pragma unroll
    for (int n2 = 0; n2 < NPB; n2++){
      float4 av = *(const float4*)(sbase + n2*288 + 4*qc);
      accv[n2] = fmaf(av.x, w0, fmaf(av.y, w1, fmaf(av.z, w2, fmaf(av.w, w3, accv[n2]))));
    }
  }
}

// ================================================================ node:
// shuffle-pipelined gather -> job-wave mix -> gate -> readout
__global__ __launch_bounds__(512)
void node_kernel(const float2* __restrict__ Tab2, const float* __restrict__ Ye,
                 const float2* __restrict__ rsp, const int* __restrict__ row_start,
                 const float* __restrict__ hg_in, float* __restrict__ hg_out,
                 const float* __restrict__ Wm_g, const float* __restrict__ Ws_g,
                 const float* __restrict__ Wp1, const float* __restrict__ Wp2,
                 const float* __restrict__ Wp3,
                 const int* __restrict__ species, const int* __restrict__ batch,
                 const float* __restrict__ ae, const float* __restrict__ charges,
                 const float* __restrict__ pos,
                 const float* __restrict__ wEv, const float* __restrict__ wDv,
                 const float* __restrict__ Whg, const float* __restrict__ wE2g,
                 int iter, float* __restrict__ out){
  __shared__ float abuf[NPB][288];    // A (gather) -> am (mixed) -> h_new
  __shared__ float sbuf[NPB][288];    // sc
  __shared__ float hstage[NPB][288];  // h_in rows, staged once
  __shared__ float glds[NG][4];
  int tid = threadIdx.x;
  if (tid < NG*4) glds[tid>>2][tid&3] = 0.f;
  int w = tid >> 6, lane = tid & 63;
  int c31 = lane & 31;
  int ng0 = blockIdx.x*NPB;
  int n = ng0 + w;

  // ---- stage h row (coalesced float4)
  {
    const float4* hrow = (const float4*)(hg_in + (size_t)n*288);
    float4* hst = (float4*)(&hstage[w][0]);
    #pragma unroll
    for (int idx = 0; idx < 2; idx++){
      int q = lane + idx*64;
      if (q < 72) hst[q] = hrow[q];
    }
  }

  // ---- gather: A[m][c] = sum_j lerp(Tab2,r_j)[col] * h_snd[c] * Ye[j][m]
  int cols[5], ms[5]; bool act5[5];
  #pragma unroll
  for (int s = 0; s < 5; s++){
    int idx = lane + s*64;
    act5[s] = (idx < 288);
    int m = act5[s] ? (idx >> 5) : 0;
    int l = (m >= 4) ? 2 : ((m >= 1) ? 1 : 0);
    cols[s] = l*32 + (idx & 31);
    ms[s] = m;
  }
  float acc[5] = {0.f,0.f,0.f,0.f,0.f};
  int jb = row_start[n], je = row_start[n+1];
  for (int j0 = jb; j0 < je; j0 += 64){
    int jl = j0 + lane;
    float2 myrs = (jl < je) ? rsp[jl] : make_float2(0.f, 0.f);
    float myr = myrs.x;
    int mysnd = __float_as_int(myrs.y);
    int cnt = je - j0; if (cnt > 64) cnt = 64;
    #pragma unroll 4
    for (int jj = 0; jj < cnt; jj++){
      float r  = __shfl(myr, jj);
      int snd  = __shfl(mysnd, jj);
      int j = j0 + jj;
      float u  = r * (TABN/5.0f);
      int i0   = (int)u;
      if (i0 > TABN-1) i0 = TABN-1;
      float f  = u - (float)i0;
      const float2* T2 = Tab2 + (size_t)i0*96;
      float hs = hg_in[(size_t)snd*288 + c31];
      const float* Yv = Ye + (size_t)j*16;
      #pragma unroll
      for (int s = 0; s < 5; s++){
        if (act5[s]){
          float2 tv = T2[cols[s]];
          float wv = fmaf(tv.y - tv.x, f, tv.x);
          acc[s] = fmaf(wv*hs, Yv[ms[s]], acc[s]);
        }
      }
    }
  }
  #pragma unroll
  for (int s = 0; s < 5; s++){
    if (act5[s]) abuf[w][lane + s*64] = acc[s] * (1.0f/16.0f);
  }
  __syncthreads();

  // ---- mix: 9 jobs over 8 waves
  // wave 0:   job A = combined slot 4 (lane<32: am m=8 from abuf; lane>=32: sc m=8 from hstage)
  //           job B = sc slot 3
  // waves 1-4: am slots 0-3;  waves 5-7: sc slots 0-2
  float accA[NPB], accB[NPB];
  #pragma unroll
  for (int n2 = 0; n2 < NPB; n2++){ accA[n2] = 0.f; accB[n2] = 0.f; }
  if (w == 0){
    const float* src = (lane < 32) ? &abuf[0][0] : &hstage[0][0];
    const float* Wg  = (lane < 32) ? Wm_g : Ws_g;
    mix_job(Wg, src, 8, c31, accA);
    int mB = (lane < 32) ? 6 : 7;               // sc slot 3: idx 192+lane
    mix_job(Ws_g, &hstage[0][0], mB, c31, accB);
  } else if (w <= 4){
    int idx0 = (w-1)*64 + lane;
    mix_job(Wm_g, &abuf[0][0], idx0 >> 5, c31, accA);
  } else {
    int idx0 = (w-5)*64 + lane;
    mix_job(Ws_g, &hstage[0][0], idx0 >> 5, c31, accA);
  }
  __syncthreads();                               // all reads of abuf done
  if (w == 0){
    if (lane < 32){
      #pragma unroll
      for (int n2 = 0; n2 < NPB; n2++) abuf[n2][256 + c31] = accA[n2];
    } else {
      #pragma unroll
      for (int n2 = 0; n2 < NPB; n2++) sbuf[n2][256 + c31] = accA[n2];
    }
    #pragma unroll
    for (int n2 = 0; n2 < NPB; n2++) sbuf[n2][192 + lane] = accB[n2];
  } else if (w <= 4){
    #pragma unroll
    for (int n2 = 0; n2 < NPB; n2++) abuf[n2][(w-1)*64 + lane] = accA[n2];
  } else {
    #pragma unroll
    for (int n2 = 0; n2 < NPB; n2++) sbuf[n2][(w-5)*64 + lane] = accA[n2];
  }
  __syncthreads();

  // ---- gate + h write (wave w = node n)
  int spec = species[n];
  float sval = abuf[w][c31];                     // am[m=0][d], broadcast
  float p1 = Wp1[spec*C+c31], p2 = Wp2[spec*C+c31], p3 = Wp3[spec*C+c31];
  float f = p1 + p2*sval + p3*sval*sval;
  #pragma unroll
  for (int it = 0; it < 5; it++){
    int idx = it*64 + lane;
    if (idx < 288){
      float hn = abuf[w][idx]*f + sbuf[w][idx];
      hg_out[(size_t)n*288 + idx] = hn;
      abuf[w][idx] = hn;
    }
  }

  // ---- readout
  int g = batch[n];
  float dv0 = 0.f, dv1 = 0.f, dv2 = 0.f, ev = 0.f;
  if (lane < 32){
    dv0 = abuf[w][32+lane]*wDv[lane];
    dv1 = abuf[w][64+lane]*wDv[lane];
    dv2 = abuf[w][96+lane]*wDv[lane];
  }
  if (iter == 0){
    if (lane < 32) ev = abuf[w][lane]*wEv[lane];
  } else {
    if (lane < 16){
      float hid = 0.f;
      #pragma unroll
      for (int c = 0; c < 32; c++) hid = fmaf(abuf[w][c], Whg[c*16+lane], hid);
      hid = silu_f(hid);
      ev = hid * wE2g[lane];
    }
  }
  #pragma unroll
  for (int off = 16; off >= 1; off >>= 1){
    ev  += __shfl_down(ev,  off);
    dv0 += __shfl_down(dv0, off);
    dv1 += __shfl_down(dv1, off);
    dv2 += __shfl_down(dv2, off);
  }
  if (lane == 0){
    if (iter == 0){
      ev += ae[spec];
      float q = charges[n];
      dv0 += q*pos[n*3+0];
      dv1 += q*pos[n*3+1];
      dv2 += q*pos[n*3+2];
    }
    atomicAdd(&glds[g][0], ev);
    atomicAdd(&glds[g][1], dv0);
    atomicAdd(&glds[g][2], dv1);
    atomicAdd(&glds[g][3], dv2);
  }
  __syncthreads();
  if (tid < NG*4){
    float v = glds[tid>>2][tid&3];
    if (v != 0.f) atomicAdd(out + tid, v);
  }
}

// ================================================================ launch
extern "C" void kernel_launch(void* const* d_in, const int* in_sizes, int n_in,
                              void* d_out, int out_size, void* d_ws, size_t ws_size,
                              hipStream_t stream){
  const float* positions       = (const float*)d_in[0];
  const float* node_attrs      = (const float*)d_in[1];
  const float* charges         = (const float*)d_in[2];
  const float* atomic_energies = (const float*)d_in[3];
  const float* W_embed         = (const float*)d_in[4];
  const float* R0              = (const float*)d_in[5];
  const float* R1              = (const float*)d_in[6];
  const float* R2              = (const float*)d_in[7];
  const float* R3              = (const float*)d_in[8];
  const float* W_mix           = (const float*)d_in[9];
  const float* W_sc            = (const float*)d_in[10];
  const float* Wp1             = (const float*)d_in[11];
  const float* Wp2             = (const float*)d_in[12];
  const float* Wp3             = (const float*)d_in[13];
  const float* wE1             = (const float*)d_in[14];
  const float* wD1             = (const float*)d_in[15];
  const float* Wh              = (const float*)d_in[16];
  const float* wE2             = (const float*)d_in[17];
  const float* wD2             = (const float*)d_in[18];
  const int*   edge_index      = (const int*)d_in[19];
  const int*   batch           = (const int*)d_in[20];
  float* out = (float*)d_out;

  char* wsp = (char*)d_ws;
  float*  Ye     = (float*)wsp;  wsp += sizeof(float)*(size_t)N_EDGES*16;
  float2* Tab2   = (float2*)wsp; wsp += sizeof(float2)*(size_t)2*TABN*96;
  float*  hg_a   = (float*)wsp;  wsp += sizeof(float)*(size_t)N_NODES*288;
  float*  hg_b   = (float*)wsp;  wsp += sizeof(float)*(size_t)N_NODES*288;
  float2* rsp    = (float2*)wsp; wsp += sizeof(float2)*(size_t)N_EDGES;
  int* counts    = (int*)wsp;    wsp += sizeof(int)*N_NODES;
  int* row_start = (int*)wsp;    wsp += sizeof(int)*(N_NODES+64);
  int* cursor    = (int*)wsp;    wsp += sizeof(int)*N_NODES;
  int* species   = (int*)wsp;    wsp += sizeof(int)*N_NODES;

  hipMemsetAsync(d_out, 0, 64*sizeof(float), stream);
  hipMemsetAsync(counts, 0, N_NODES*sizeof(int), stream);

  prep_kernel<<<802, 256, 0, stream>>>(positions, edge_index, counts,
                                       node_attrs, W_embed, species, hg_a,
                                       R0, R1, R2, R3, Tab2);
  scan_kernel<<<1, 256, 0, stream>>>(counts, row_start, cursor);
  fill_geom_kernel<<<N_EDGES/256, 256, 0, stream>>>(positions, edge_index, cursor, Ye, rsp);

  for (int i = 0; i < 2; i++){
    const float* hin  = (i == 0) ? hg_a : hg_b;
    float*       hout = (i == 0) ? hg_b : hg_a;
    node_kernel<<<N_NODES/NPB, 512, 0, stream>>>(Tab2 + (size_t)i*TABN*96, Ye,
                                               rsp, row_start, hin, hout,
                                               W_mix + i*3*C*C, W_sc + i*3*C*C,
                                               Wp1 + i*Zn*C, Wp2 + i*Zn*C, Wp3 + i*Zn*C,
                                               species, batch,
                                               atomic_energies, charges, positions,
                                               wE1, (i == 0) ? wD1 : wD2,
                                               Wh, wE2, i, out);
  }
}

// Round 9
// 276.727 us; speedup vs baseline: 1.1356x; 1.1356x over previous
//
#include <hip/hip_runtime.h>
#include <math.h>

#define N_NODES 8192
#define N_EDGES 131072
#define C 32
#define Zn 10
#define NG 16
#define NB 8
#define H 64
#define TABN 4096
#define PPB 32     // table points per block
#define XS 73      // table activation LDS stride
#define NPB 8      // nodes per node_kernel block
#define CAP 64     // bucket capacity per node (max in-degree ~40)

__device__ __forceinline__ float silu_f(float v){ return v / (1.0f + __expf(-v)); }

// ================================================================ prep (fused):
// blocks [0,512): edge geometry + bucket fill (no hist/scan needed)
// blocks [512,544): species + h0 (cols 0..31; zeros from memset)
// blocks [544,802): radial MLP tables (both iterations, interleaved lerp pairs)
__global__ __launch_bounds__(256)
void prep_kernel(const float* __restrict__ pos, const int* __restrict__ ei,
                 int* __restrict__ cursor, float* __restrict__ Ye,
                 float2* __restrict__ rsp,
                 const float* __restrict__ na, const float* __restrict__ Wemb,
                 int* __restrict__ species, float* __restrict__ hg,
                 const float* __restrict__ R0g, const float* __restrict__ R1g,
                 const float* __restrict__ R2g, const float* __restrict__ R3g,
                 float2* __restrict__ Tab2){
  __shared__ float xsh[PPB*XS];
  int b = blockIdx.x;
  int tid = threadIdx.x;

  if (b < 512){
    int e = b*256 + tid;
    int snd = ei[e], rcv = ei[N_EDGES + e];
    float px = pos[rcv*3+0]-pos[snd*3+0];
    float py = pos[rcv*3+1]-pos[snd*3+1];
    float pz = pos[rcv*3+2]-pos[snd*3+2];
    float r = sqrtf(px*px+py*py+pz*pz + 1e-12f);
    if (r < 5.0f){
      int slot = atomicAdd(cursor + rcv, 1);
      if (slot < CAP){
        int p = rcv*CAP + slot;
        float inv = 1.0f/r;
        float x = px*inv, y = py*inv, z = pz*inv;
        const float s3 = 1.7320508075688772f;
        const float s5 = 2.23606797749979f;
        const float s15 = 3.872983346207417f;
        float* ye = Ye + (size_t)p*16;
        *(float4*)(ye)   = make_float4(1.f, s3*x, s3*y, s3*z);
        *(float4*)(ye+4) = make_float4(s15*x*y, s15*y*z, 0.5f*s5*(3.f*z*z-1.f), s15*x*z);
        ye[8] = 0.5f*s15*(x*x-y*y);
        rsp[p] = make_float2(r, __int_as_float(snd));
      }
    }
    return;
  }
  if (b < 544){
    int n = (b-512)*256 + tid;
    int spec = 0;
    #pragma unroll
    for (int z = 1; z < Zn; z++) if (na[n*Zn+z] > 0.5f) spec = z;
    species[n] = spec;
    float4* hrow = (float4*)(hg + (size_t)n*288);
    const float4* wrow = (const float4*)(Wemb + spec*C);
    #pragma unroll
    for (int q = 0; q < 8; q++) hrow[q] = wrow[q];
    return;
  }

  // ---- table part
  int tb = b - 544;
  const int nb = (TABN + PPB)/PPB;   // 129
  int half = tb / nb;
  int blk  = tb - half*nb;
  const float* R0i = R0g + half*NB*H;
  const float* R1i = R1g + half*H*H;
  const float* R2i = R2g + half*H*H;
  const float* R3i = R3g + half*H*96;
  float2* TabH = Tab2 + (size_t)half*((size_t)TABN*96);

  int pl = tid >> 3, jt = tid & 7;
  int i = blk*PPB + pl;
  float r = (i == 0) ? 1e-6f : (float)i * (5.0f/TABN);
  {
    float xr = r*0.2f;
    float env = 0.f;
    if (xr < 1.0f){
      float x2 = xr*xr, x5 = x2*x2*xr;
      env = 1.f - 21.f*x5 + 35.f*x5*xr - 15.f*x5*x2;
    }
    float sc = 0.6324555320336759f / r * env;
    xsh[pl*XS + jt] = sc * sinf((float)(jt+1)*0.6283185307179586f*r);
  }
  __syncthreads();

  float acc[12];
  #pragma unroll
  for (int j = 0; j < 8; j++) acc[j] = 0.f;
  #pragma unroll
  for (int k = 0; k < 8; k++){
    float xk = xsh[pl*XS + k];
    const float4* w4 = (const float4*)(R0i + k*H + jt*8);
    float4 wa = w4[0], wb = w4[1];
    acc[0]=fmaf(xk,wa.x,acc[0]); acc[1]=fmaf(xk,wa.y,acc[1]);
    acc[2]=fmaf(xk,wa.z,acc[2]); acc[3]=fmaf(xk,wa.w,acc[3]);
    acc[4]=fmaf(xk,wb.x,acc[4]); acc[5]=fmaf(xk,wb.y,acc[5]);
    acc[6]=fmaf(xk,wb.z,acc[6]); acc[7]=fmaf(xk,wb.w,acc[7]);
  }
  __syncthreads();
  #pragma unroll
  for (int j = 0; j < 8; j++) xsh[pl*XS + jt*8 + j] = silu_f(acc[j]);
  __syncthreads();

  const float* Wl[2] = {R1i, R2i};
  #pragma unroll
  for (int L = 0; L < 2; L++){
    const float* W = Wl[L];
    #pragma unroll
    for (int j = 0; j < 8; j++) acc[j] = 0.f;
    for (int k = 0; k < H; k++){
      float xk = xsh[pl*XS + k];
      const float4* w4 = (const float4*)(W + k*H + jt*8);
      float4 wa = w4[0], wb = w4[1];
      acc[0]=fmaf(xk,wa.x,acc[0]); acc[1]=fmaf(xk,wa.y,acc[1]);
      acc[2]=fmaf(xk,wa.z,acc[2]); acc[3]=fmaf(xk,wa.w,acc[3]);
      acc[4]=fmaf(xk,wb.x,acc[4]); acc[5]=fmaf(xk,wb.y,acc[5]);
      acc[6]=fmaf(xk,wb.z,acc[6]); acc[7]=fmaf(xk,wb.w,acc[7]);
    }
    __syncthreads();
    #pragma unroll
    for (int j = 0; j < 8; j++) xsh[pl*XS + jt*8 + j] = silu_f(acc[j]);
    __syncthreads();
  }

  #pragma unroll
  for (int j = 0; j < 12; j++) acc[j] = 0.f;
  for (int k = 0; k < H; k++){
    float xk = xsh[pl*XS + k];
    const float4* w4 = (const float4*)(R3i + k*96 + jt*12);
    float4 wa = w4[0], wb = w4[1], wc = w4[2];
    acc[0]=fmaf(xk,wa.x,acc[0]);  acc[1]=fmaf(xk,wa.y,acc[1]);
    acc[2]=fmaf(xk,wa.z,acc[2]);  acc[3]=fmaf(xk,wa.w,acc[3]);
    acc[4]=fmaf(xk,wb.x,acc[4]);  acc[5]=fmaf(xk,wb.y,acc[5]);
    acc[6]=fmaf(xk,wb.z,acc[6]);  acc[7]=fmaf(xk,wb.w,acc[7]);
    acc[8]=fmaf(xk,wc.x,acc[8]);  acc[9]=fmaf(xk,wc.y,acc[9]);
    acc[10]=fmaf(xk,wc.z,acc[10]); acc[11]=fmaf(xk,wc.w,acc[11]);
  }
  if (i <= TABN){
    int cb = jt*12;
    #pragma unroll
    for (int j = 0; j < 12; j++){
      int c = cb + j;
      float val = acc[j];
      if (i < TABN) TabH[(size_t)i*96 + c].x = val;      // lerp lower endpoint
      if (i > 0)    TabH[(size_t)(i-1)*96 + c].y = val;  // lerp upper endpoint
    }
  }
}

// ================================================================ node:
// gather (lerp table) -> slot-wave mix (transposed-weight LDS) -> gate -> readout
__global__ __launch_bounds__(512)
void node_kernel(const float2* __restrict__ Tab2, const float* __restrict__ Ye,
                 const float2* __restrict__ rsp, const int* __restrict__ deg,
                 const float* __restrict__ hg_in, float* __restrict__ hg_out,
                 const float* __restrict__ Wm_g, const float* __restrict__ Ws_g,
                 const float* __restrict__ Wp1, const float* __restrict__ Wp2,
                 const float* __restrict__ Wp3,
                 const int* __restrict__ species, const int* __restrict__ batch,
                 const float* __restrict__ ae, const float* __restrict__ charges,
                 const float* __restrict__ pos,
                 const float* __restrict__ wEv, const float* __restrict__ wDv,
                 const float* __restrict__ Whg, const float* __restrict__ wE2g,
                 int iter, float* __restrict__ out){
  __shared__ float WmT[3*32*34];      // [l][d][c], stride 34 (2-way banks, b64-aligned)
  __shared__ float WsT[3*32*34];
  __shared__ float abuf[NPB][288];    // A (gather) -> A-mixed -> h_new
  __shared__ float sbuf[NPB][288];    // sc
  __shared__ float glds[NG][4];
  int tid = threadIdx.x;
  for (int t = tid; t < 3072; t += 512){
    int l = t >> 10, rem = t & 1023, c = rem >> 5, d = rem & 31;
    WmT[(l*32+d)*34 + c] = Wm_g[t];
    WsT[(l*32+d)*34 + c] = Ws_g[t];
  }
  if (tid < NG*4) glds[tid>>2][tid&3] = 0.f;
  int w = tid >> 6, lane = tid & 63;
  int c31 = lane & 31;
  int ng0 = blockIdx.x*NPB;
  int n = ng0 + w;

  // ---- gather: A[m][c] = sum_j lerp(Tab2,r_j)[col] * h_snd[c] * Ye[j][m]
  int cols[5], ms[5]; bool act5[5];
  #pragma unroll
  for (int s = 0; s < 5; s++){
    int idx = lane + s*64;
    act5[s] = (idx < 288);
    int m = act5[s] ? (idx >> 5) : 0;
    int l = (m >= 4) ? 2 : ((m >= 1) ? 1 : 0);
    cols[s] = l*32 + (idx & 31);
    ms[s] = m;
  }
  float acc[5] = {0.f,0.f,0.f,0.f,0.f};
  int jb = n*CAP;
  int cnt = deg[n]; if (cnt > CAP) cnt = CAP;
  int je = jb + cnt;
  #pragma unroll 2
  for (int j = jb; j < je; j++){
    float2 rs = rsp[j];                        // wave-uniform
    float r  = rs.x;
    int snd  = __float_as_int(rs.y);
    float u  = r * (TABN/5.0f);
    int i0   = (int)u;
    if (i0 > TABN-1) i0 = TABN-1;
    float f  = u - (float)i0;
    const float2* T2 = Tab2 + (size_t)i0*96;
    float hs = hg_in[(size_t)snd*288 + c31];
    const float* Yv = Ye + (size_t)j*16;
    #pragma unroll
    for (int s = 0; s < 5; s++){
      if (act5[s]){
        float2 tv = T2[cols[s]];
        float wv = fmaf(tv.y - tv.x, f, tv.x);
        acc[s] = fmaf(wv*hs, Yv[ms[s]], acc[s]);
      }
    }
  }
  #pragma unroll
  for (int s = 0; s < 5; s++){
    if (act5[s]) abuf[w][lane + s*64] = acc[s] * (1.0f/16.0f);
  }
  __syncthreads();

  // ---- mix: waves 0..4 each own one slot (s=w) across all 8 nodes
  float a2[NPB], scv[NPB];
  int idx0 = w*64 + lane;
  bool actm = (w < 5) && (idx0 < 288);
  if (w < 5){
    int m = idx0 >> 5; if (m > 8) m = 8;       // clamp keeps reads in-bounds
    int l = (m >= 4) ? 2 : ((m >= 1) ? 1 : 0);
    const float* wmB = WmT + (l*32 + c31)*34;
    const float* wsB = WsT + (l*32 + c31)*34;
    #pragma unroll
    for (int n2 = 0; n2 < NPB; n2++){ a2[n2] = 0.f; scv[n2] = 0.f; }
    #pragma unroll
    for (int q = 0; q < 8; q++){
      float2 wa0 = *(const float2*)(wmB + 4*q);
      float2 wa1 = *(const float2*)(wmB + 4*q + 2);
      float2 sa0 = *(const float2*)(wsB + 4*q);
      float2 sa1 = *(const float2*)(wsB + 4*q + 2);
      #pragma unroll
      for (int n2 = 0; n2 < NPB; n2++){
        float4 av = *(const float4*)(&abuf[n2][m*32 + 4*q]);
        float4 hv = *(const float4*)(hg_in + (size_t)(ng0+n2)*288 + m*32 + 4*q);
        a2[n2] = fmaf(av.x, wa0.x, a2[n2]); a2[n2] = fmaf(av.y, wa0.y, a2[n2]);
        a2[n2] = fmaf(av.z, wa1.x, a2[n2]); a2[n2] = fmaf(av.w, wa1.y, a2[n2]);
        scv[n2] = fmaf(hv.x, sa0.x, scv[n2]); scv[n2] = fmaf(hv.y, sa0.y, scv[n2]);
        scv[n2] = fmaf(hv.z, sa1.x, scv[n2]); scv[n2] = fmaf(hv.w, sa1.y, scv[n2]);
      }
    }
  }
  __syncthreads();                              // all A reads done
  if (actm){
    #pragma unroll
    for (int n2 = 0; n2 < NPB; n2++){
      abuf[n2][idx0] = a2[n2];
      sbuf[n2][idx0] = scv[n2];
    }
  }
  __syncthreads();

  // ---- gate + h write (wave w = node n)
  int spec = species[n];
  float sval = abuf[w][c31];                    // A-mixed[m=0][d]
  float p1 = Wp1[spec*C+c31], p2 = Wp2[spec*C+c31], p3 = Wp3[spec*C+c31];
  float f = p1 + p2*sval + p3*sval*sval;
  #pragma unroll
  for (int it = 0; it < 5; it++){
    int idx = it*64 + lane;
    if (idx < 288){
      float hn = abuf[w][idx]*f + sbuf[w][idx];
      hg_out[(size_t)n*288 + idx] = hn;
      abuf[w][idx] = hn;                        // same-lane RAW, wave-local
    }
  }

  // ---- readout
  int g = batch[n];
  float dv0 = 0.f, dv1 = 0.f, dv2 = 0.f, ev = 0.f;
  if (lane < 32){
    dv0 = abuf[w][32+lane]*wDv[lane];
    dv1 = abuf[w][64+lane]*wDv[lane];
    dv2 = abuf[w][96+lane]*wDv[lane];
  }
  if (iter == 0){
    if (lane < 32) ev = abuf[w][lane]*wEv[lane];
  } else {
    if (lane < 16){
      float hid = 0.f;
      #pragma unroll
      for (int c = 0; c < 32; c++) hid = fmaf(abuf[w][c], Whg[c*16+lane], hid);
      hid = silu_f(hid);
      ev = hid * wE2g[lane];
    }
  }
  #pragma unroll
  for (int off = 16; off >= 1; off >>= 1){
    ev  += __shfl_down(ev,  off);
    dv0 += __shfl_down(dv0, off);
    dv1 += __shfl_down(dv1, off);
    dv2 += __shfl_down(dv2, off);
  }
  if (lane == 0){
    if (iter == 0){                             // fold in e0 + charge-dipole baseline
      ev += ae[spec];
      float q = charges[n];
      dv0 += q*pos[n*3+0];
      dv1 += q*pos[n*3+1];
      dv2 += q*pos[n*3+2];
    }
    atomicAdd(&glds[g][0], ev);
    atomicAdd(&glds[g][1], dv0);
    atomicAdd(&glds[g][2], dv1);
    atomicAdd(&glds[g][3], dv2);
  }
  __syncthreads();
  if (tid < NG*4){
    float v = glds[tid>>2][tid&3];
    if (v != 0.f) atomicAdd(out + tid, v);
  }
}

// ================================================================ launch
extern "C" void kernel_launch(void* const* d_in, const int* in_sizes, int n_in,
                              void* d_out, int out_size, void* d_ws, size_t ws_size,
                              hipStream_t stream){
  const float* positions       = (const float*)d_in[0];
  const float* node_attrs      = (const float*)d_in[1];
  const float* charges         = (const float*)d_in[2];
  const float* atomic_energies = (const float*)d_in[3];
  const float* W_embed         = (const float*)d_in[4];
  const float* R0              = (const float*)d_in[5];
  const float* R1              = (const float*)d_in[6];
  const float* R2              = (const float*)d_in[7];
  const float* R3              = (const float*)d_in[8];
  const float* W_mix           = (const float*)d_in[9];
  const float* W_sc            = (const float*)d_in[10];
  const float* Wp1             = (const float*)d_in[11];
  const float* Wp2             = (const float*)d_in[12];
  const float* Wp3             = (const float*)d_in[13];
  const float* wE1             = (const float*)d_in[14];
  const float* wD1             = (const float*)d_in[15];
  const float* Wh              = (const float*)d_in[16];
  const float* wE2             = (const float*)d_in[17];
  const float* wD2             = (const float*)d_in[18];
  const int*   edge_index      = (const int*)d_in[19];
  const int*   batch           = (const int*)d_in[20];
  float* out = (float*)d_out;

  char* wsp = (char*)d_ws;
  float*  Ye     = (float*)wsp;  wsp += sizeof(float)*(size_t)N_NODES*CAP*16;
  float2* rsp    = (float2*)wsp; wsp += sizeof(float2)*(size_t)N_NODES*CAP;
  float2* Tab2   = (float2*)wsp; wsp += sizeof(float2)*(size_t)2*TABN*96;
  float*  hg_a   = (float*)wsp;  wsp += sizeof(float)*(size_t)N_NODES*288;
  float*  hg_b   = (float*)wsp;  wsp += sizeof(float)*(size_t)N_NODES*288;
  int* cursor    = (int*)wsp;    wsp += sizeof(int)*N_NODES;
  int* species   = (int*)wsp;    wsp += sizeof(int)*N_NODES;

  hipMemsetAsync(d_out, 0, 64*sizeof(float), stream);
  hipMemsetAsync(cursor, 0, N_NODES*sizeof(int), stream);
  hipMemsetAsync(hg_a, 0, sizeof(float)*(size_t)N_NODES*288, stream);

  prep_kernel<<<802, 256, 0, stream>>>(positions, edge_index, cursor, Ye, rsp,
                                       node_attrs, W_embed, species, hg_a,
                                       R0, R1, R2, R3, Tab2);

  for (int i = 0; i < 2; i++){
    const float* hin  = (i == 0) ? hg_a : hg_b;
    float*       hout = (i == 0) ? hg_b : hg_a;
    node_kernel<<<N_NODES/NPB, 512, 0, stream>>>(Tab2 + (size_t)i*TABN*96, Ye,
                                               rsp, cursor, hin, hout,
                                               W_mix + i*3*C*C, W_sc + i*3*C*C,
                                               Wp1 + i*Zn*C, Wp2 + i*Zn*C, Wp3 + i*Zn*C,
                                               species, batch,
                                               atomic_energies, charges, positions,
                                               wE1, (i == 0) ? wD1 : wD2,
                                               Wh, wE2, i, out);
  }
}

// Round 10
// 262.255 us; speedup vs baseline: 1.1983x; 1.0552x over previous
//
#include <hip/hip_runtime.h>
#include <math.h>

#define N_NODES 8192
#define N_EDGES 131072
#define C 32
#define Zn 10
#define NG 16
#define NB 8
#define H 64
#define TABN 4096
#define PPB 32     // table points per block
#define XS 73      // table activation LDS stride
#define NPB 4      // nodes per node_kernel block (2 waves per node)
#define CAP 64     // bucket capacity per node (max in-degree ~40)

__device__ __forceinline__ float silu_f(float v){ return v / (1.0f + __expf(-v)); }

// ================================================================ prep (fused):
// blocks [0,512): edge geometry + bucket fill (32B records, no hist/scan)
// blocks [512,544): species + h0 (cols 0..31; zeros from memset)
// blocks [544,802): radial MLP tables (both iterations, interleaved lerp pairs)
__global__ __launch_bounds__(256)
void prep_kernel(const float* __restrict__ pos, const int* __restrict__ ei,
                 int* __restrict__ cursor, float4* __restrict__ erec,
                 const float* __restrict__ na, const float* __restrict__ Wemb,
                 int* __restrict__ species, float* __restrict__ hg,
                 const float* __restrict__ R0g, const float* __restrict__ R1g,
                 const float* __restrict__ R2g, const float* __restrict__ R3g,
                 float2* __restrict__ Tab2){
  __shared__ float xsh[PPB*XS];
  int b = blockIdx.x;
  int tid = threadIdx.x;

  if (b < 512){
    int e = b*256 + tid;
    int snd = ei[e], rcv = ei[N_EDGES + e];
    float px = pos[rcv*3+0]-pos[snd*3+0];
    float py = pos[rcv*3+1]-pos[snd*3+1];
    float pz = pos[rcv*3+2]-pos[snd*3+2];
    float r = sqrtf(px*px+py*py+pz*pz + 1e-12f);
    if (r < 5.0f){
      int slot = atomicAdd(cursor + rcv, 1);
      if (slot < CAP){
        int p = rcv*CAP + slot;
        float inv = 1.0f/r;
        erec[2*p]   = make_float4(px*inv, py*inv, pz*inv, r);
        erec[2*p+1] = make_float4(__int_as_float(snd), 0.f, 0.f, 0.f);
      }
    }
    return;
  }
  if (b < 544){
    int n = (b-512)*256 + tid;
    int spec = 0;
    #pragma unroll
    for (int z = 1; z < Zn; z++) if (na[n*Zn+z] > 0.5f) spec = z;
    species[n] = spec;
    float4* hrow = (float4*)(hg + (size_t)n*288);
    const float4* wrow = (const float4*)(Wemb + spec*C);
    #pragma unroll
    for (int q = 0; q < 8; q++) hrow[q] = wrow[q];
    return;
  }

  // ---- table part
  int tb = b - 544;
  const int nb = (TABN + PPB)/PPB;   // 129
  int half = tb / nb;
  int blk  = tb - half*nb;
  const float* R0i = R0g + half*NB*H;
  const float* R1i = R1g + half*H*H;
  const float* R2i = R2g + half*H*H;
  const float* R3i = R3g + half*H*96;
  float2* TabH = Tab2 + (size_t)half*((size_t)TABN*96);

  int pl = tid >> 3, jt = tid & 7;
  int i = blk*PPB + pl;
  float r = (i == 0) ? 1e-6f : (float)i * (5.0f/TABN);
  {
    float xr = r*0.2f;
    float env = 0.f;
    if (xr < 1.0f){
      float x2 = xr*xr, x5 = x2*x2*xr;
      env = 1.f - 21.f*x5 + 35.f*x5*xr - 15.f*x5*x2;
    }
    float sc = 0.6324555320336759f / r * env;
    xsh[pl*XS + jt] = sc * sinf((float)(jt+1)*0.6283185307179586f*r);
  }
  __syncthreads();

  float acc[12];
  #pragma unroll
  for (int j = 0; j < 8; j++) acc[j] = 0.f;
  #pragma unroll
  for (int k = 0; k < 8; k++){
    float xk = xsh[pl*XS + k];
    const float4* w4 = (const float4*)(R0i + k*H + jt*8);
    float4 wa = w4[0], wb = w4[1];
    acc[0]=fmaf(xk,wa.x,acc[0]); acc[1]=fmaf(xk,wa.y,acc[1]);
    acc[2]=fmaf(xk,wa.z,acc[2]); acc[3]=fmaf(xk,wa.w,acc[3]);
    acc[4]=fmaf(xk,wb.x,acc[4]); acc[5]=fmaf(xk,wb.y,acc[5]);
    acc[6]=fmaf(xk,wb.z,acc[6]); acc[7]=fmaf(xk,wb.w,acc[7]);
  }
  __syncthreads();
  #pragma unroll
  for (int j = 0; j < 8; j++) xsh[pl*XS + jt*8 + j] = silu_f(acc[j]);
  __syncthreads();

  const float* Wl[2] = {R1i, R2i};
  #pragma unroll
  for (int L = 0; L < 2; L++){
    const float* W = Wl[L];
    #pragma unroll
    for (int j = 0; j < 8; j++) acc[j] = 0.f;
    for (int k = 0; k < H; k++){
      float xk = xsh[pl*XS + k];
      const float4* w4 = (const float4*)(W + k*H + jt*8);
      float4 wa = w4[0], wb = w4[1];
      acc[0]=fmaf(xk,wa.x,acc[0]); acc[1]=fmaf(xk,wa.y,acc[1]);
      acc[2]=fmaf(xk,wa.z,acc[2]); acc[3]=fmaf(xk,wa.w,acc[3]);
      acc[4]=fmaf(xk,wb.x,acc[4]); acc[5]=fmaf(xk,wb.y,acc[5]);
      acc[6]=fmaf(xk,wb.z,acc[6]); acc[7]=fmaf(xk,wb.w,acc[7]);
    }
    __syncthreads();
    #pragma unroll
    for (int j = 0; j < 8; j++) xsh[pl*XS + jt*8 + j] = silu_f(acc[j]);
    __syncthreads();
  }

  #pragma unroll
  for (int j = 0; j < 12; j++) acc[j] = 0.f;
  for (int k = 0; k < H; k++){
    float xk = xsh[pl*XS + k];
    const float4* w4 = (const float4*)(R3i + k*96 + jt*12);
    float4 wa = w4[0], wb = w4[1], wc = w4[2];
    acc[0]=fmaf(xk,wa.x,acc[0]);  acc[1]=fmaf(xk,wa.y,acc[1]);
    acc[2]=fmaf(xk,wa.z,acc[2]);  acc[3]=fmaf(xk,wa.w,acc[3]);
    acc[4]=fmaf(xk,wb.x,acc[4]);  acc[5]=fmaf(xk,wb.y,acc[5]);
    acc[6]=fmaf(xk,wb.z,acc[6]);  acc[7]=fmaf(xk,wb.w,acc[7]);
    acc[8]=fmaf(xk,wc.x,acc[8]);  acc[9]=fmaf(xk,wc.y,acc[9]);
    acc[10]=fmaf(xk,wc.z,acc[10]); acc[11]=fmaf(xk,wc.w,acc[11]);
  }
  if (i <= TABN){
    int cb = jt*12;
    #pragma unroll
    for (int j = 0; j < 12; j++){
      int c = cb + j;
      float val = acc[j];
      if (i < TABN) TabH[(size_t)i*96 + c].x = val;      // lerp lower endpoint
      if (i > 0)    TabH[(size_t)(i-1)*96 + c].y = val;  // lerp upper endpoint
    }
  }
}

// ================================================================ node:
// 2-wave-per-node gather (in-register Y, 3 table loads/edge) -> slot-wave mix -> gate -> readout
__global__ __launch_bounds__(512)
void node_kernel(const float2* __restrict__ Tab2, const float4* __restrict__ erec,
                 const int* __restrict__ deg,
                 const float* __restrict__ hg_in, float* __restrict__ hg_out,
                 const float* __restrict__ Wm_g, const float* __restrict__ Ws_g,
                 const float* __restrict__ Wp1, const float* __restrict__ Wp2,
                 const float* __restrict__ Wp3,
                 const int* __restrict__ species, const int* __restrict__ batch,
                 const float* __restrict__ ae, const float* __restrict__ charges,
                 const float* __restrict__ pos,
                 const float* __restrict__ wEv, const float* __restrict__ wDv,
                 const float* __restrict__ Whg, const float* __restrict__ wE2g,
                 int iter, float* __restrict__ out){
  __shared__ float WmT[3*32*34];      // [l][d][c], stride 34
  __shared__ float WsT[3*32*34];
  __shared__ float abuf[NPB][288];    // A (gather) -> A-mixed -> h_new
  __shared__ float sbuf[NPB][288];    // gather partials -> sc
  __shared__ float glds[NG][4];
  int tid = threadIdx.x;
  for (int t = tid; t < 3072; t += 512){
    int l = t >> 10, rem = t & 1023, c = rem >> 5, d = rem & 31;
    WmT[(l*32+d)*34 + c] = Wm_g[t];
    WsT[(l*32+d)*34 + c] = Ws_g[t];
  }
  if (tid < NG*4) glds[tid>>2][tid&3] = 0.f;
  int w = tid >> 6, lane = tid & 63;
  int c31 = lane & 31;
  bool hi = lane >= 32;
  int ng0 = blockIdx.x*NPB;
  int nw = w & 3;            // node within block
  int halfw = w >> 2;        // 0: even slots, 1: odd slots
  int n = ng0 + nw;

  // ---- gather: acc[s] over this wave's slots
  const float s3 = 1.7320508075688772f;
  const float s5 = 2.23606797749979f;
  const float s15 = 3.872983346207417f;
  int colA = (hi ? 32 : 0) + c31;    // s=0: l=0(m0) / l=1(m1)
  int colB = 32 + c31;               // s=1: m2,m3 -> l=1
  int colC = 64 + c31;               // s=2,3,4: l=2
  float acc0=0.f, acc1=0.f, acc2=0.f, acc3=0.f, acc4=0.f;
  int cnt = deg[n]; if (cnt > CAP) cnt = CAP;
  int jb = n*CAP;
  #pragma unroll 2
  for (int s_ = halfw; s_ < cnt; s_ += 2){
    const float4* rp = erec + 2*(jb + s_);
    float4 ra = rp[0];
    int snd = __float_as_int(rp[1].x);
    float x = ra.x, y = ra.y, z = ra.z, r = ra.w;
    float u  = r * (TABN/5.0f);
    int i0   = (int)u;
    if (i0 > TABN-1) i0 = TABN-1;
    float f  = u - (float)i0;
    const float2* T2 = Tab2 + (size_t)i0*96;
    float hs = hg_in[(size_t)snd*288 + c31];
    float2 ta = T2[colA];
    float2 tb = T2[colB];
    float2 tc = T2[colC];
    float wv0 = fmaf(ta.y - ta.x, f, ta.x) * hs;
    float wv1 = fmaf(tb.y - tb.x, f, tb.x) * hs;
    float wv2 = fmaf(tc.y - tc.x, f, tc.x) * hs;
    float Ys0 = hi ? s3*x : 1.0f;
    float Ys1 = s3 * (hi ? z : y);
    float Ys2 = s15 * (hi ? y*z : x*y);
    float Ys3 = hi ? s15*x*z : 0.5f*s5*(3.f*z*z - 1.f);
    float Ys4 = 0.5f*s15*(x*x - y*y);
    acc0 = fmaf(wv0, Ys0, acc0);
    acc1 = fmaf(wv1, Ys1, acc1);
    acc2 = fmaf(wv2, Ys2, acc2);
    acc3 = fmaf(wv2, Ys3, acc3);
    acc4 = fmaf(wv2, Ys4, acc4);
  }
  // combine the two half-waves
  if (halfw == 1){
    sbuf[nw][lane]       = acc0;
    sbuf[nw][lane + 64]  = acc1;
    sbuf[nw][lane + 128] = acc2;
    sbuf[nw][lane + 192] = acc3;
    if (!hi) sbuf[nw][lane + 256] = acc4;
  }
  __syncthreads();
  if (halfw == 0){
    abuf[nw][lane]       = (acc0 + sbuf[nw][lane])       * (1.0f/16.0f);
    abuf[nw][lane + 64]  = (acc1 + sbuf[nw][lane + 64])  * (1.0f/16.0f);
    abuf[nw][lane + 128] = (acc2 + sbuf[nw][lane + 128]) * (1.0f/16.0f);
    abuf[nw][lane + 192] = (acc3 + sbuf[nw][lane + 192]) * (1.0f/16.0f);
    if (!hi) abuf[nw][lane + 256] = (acc4 + sbuf[nw][lane + 256]) * (1.0f/16.0f);
  }
  __syncthreads();

  // ---- mix: waves 0..4 each own slot w across the 4 nodes
  float a2[NPB], scv[NPB];
  int idx0 = w*64 + lane;
  bool actm = (w < 5) && (idx0 < 288);
  if (w < 5){
    int m = idx0 >> 5; if (m > 8) m = 8;
    int l = (m >= 4) ? 2 : ((m >= 1) ? 1 : 0);
    const float* wmB = WmT + (l*32 + c31)*34;
    const float* wsB = WsT + (l*32 + c31)*34;
    #pragma unroll
    for (int n2 = 0; n2 < NPB; n2++){ a2[n2] = 0.f; scv[n2] = 0.f; }
    #pragma unroll
    for (int q = 0; q < 8; q++){
      float2 wa0 = *(const float2*)(wmB + 4*q);
      float2 wa1 = *(const float2*)(wmB + 4*q + 2);
      float2 sa0 = *(const float2*)(wsB + 4*q);
      float2 sa1 = *(const float2*)(wsB + 4*q + 2);
      #pragma unroll
      for (int n2 = 0; n2 < NPB; n2++){
        float4 av = *(const float4*)(&abuf[n2][m*32 + 4*q]);
        float4 hv = *(const float4*)(hg_in + (size_t)(ng0+n2)*288 + m*32 + 4*q);
        a2[n2] = fmaf(av.x, wa0.x, a2[n2]); a2[n2] = fmaf(av.y, wa0.y, a2[n2]);
        a2[n2] = fmaf(av.z, wa1.x, a2[n2]); a2[n2] = fmaf(av.w, wa1.y, a2[n2]);
        scv[n2] = fmaf(hv.x, sa0.x, scv[n2]); scv[n2] = fmaf(hv.y, sa0.y, scv[n2]);
        scv[n2] = fmaf(hv.z, sa1.x, scv[n2]); scv[n2] = fmaf(hv.w, sa1.y, scv[n2]);
      }
    }
  }
  __syncthreads();                              // all A reads done
  if (actm){
    #pragma unroll
    for (int n2 = 0; n2 < NPB; n2++){
      abuf[n2][idx0] = a2[n2];
      sbuf[n2][idx0] = scv[n2];
    }
  }
  __syncthreads();

  // ---- gate + h write + readout (waves 0..3, wave w = node ng0+w)
  if (w < 4){
    int nn = ng0 + w;
    int spec = species[nn];
    float sval = abuf[w][c31];
    float p1 = Wp1[spec*C+c31], p2 = Wp2[spec*C+c31], p3 = Wp3[spec*C+c31];
    float f = p1 + p2*sval + p3*sval*sval;
    #pragma unroll
    for (int it = 0; it < 5; it++){
      int idx = it*64 + lane;
      if (idx < 288){
        float hn = abuf[w][idx]*f + sbuf[w][idx];
        hg_out[(size_t)nn*288 + idx] = hn;
        abuf[w][idx] = hn;
      }
    }

    int g = batch[nn];
    float dv0 = 0.f, dv1 = 0.f, dv2 = 0.f, ev = 0.f;
    if (lane < 32){
      dv0 = abuf[w][32+lane]*wDv[lane];
      dv1 = abuf[w][64+lane]*wDv[lane];
      dv2 = abuf[w][96+lane]*wDv[lane];
    }
    if (iter == 0){
      if (lane < 32) ev = abuf[w][lane]*wEv[lane];
    } else {
      if (lane < 16){
        float hid = 0.f;
        #pragma unroll
        for (int c = 0; c < 32; c++) hid = fmaf(abuf[w][c], Whg[c*16+lane], hid);
        hid = silu_f(hid);
        ev = hid * wE2g[lane];
      }
    }
    #pragma unroll
    for (int off = 16; off >= 1; off >>= 1){
      ev  += __shfl_down(ev,  off);
      dv0 += __shfl_down(dv0, off);
      dv1 += __shfl_down(dv1, off);
      dv2 += __shfl_down(dv2, off);
    }
    if (lane == 0){
      if (iter == 0){
        ev += ae[spec];
        float q = charges[nn];
        dv0 += q*pos[nn*3+0];
        dv1 += q*pos[nn*3+1];
        dv2 += q*pos[nn*3+2];
      }
      atomicAdd(&glds[g][0], ev);
      atomicAdd(&glds[g][1], dv0);
      atomicAdd(&glds[g][2], dv1);
      atomicAdd(&glds[g][3], dv2);
    }
  }
  __syncthreads();
  if (tid < NG*4){
    float v = glds[tid>>2][tid&3];
    if (v != 0.f) atomicAdd(out + tid, v);
  }
}

// ================================================================ launch
extern "C" void kernel_launch(void* const* d_in, const int* in_sizes, int n_in,
                              void* d_out, int out_size, void* d_ws, size_t ws_size,
                              hipStream_t stream){
  const float* positions       = (const float*)d_in[0];
  const float* node_attrs      = (const float*)d_in[1];
  const float* charges         = (const float*)d_in[2];
  const float* atomic_energies = (const float*)d_in[3];
  const float* W_embed         = (const float*)d_in[4];
  const float* R0              = (const float*)d_in[5];
  const float* R1              = (const float*)d_in[6];
  const float* R2              = (const float*)d_in[7];
  const float* R3              = (const float*)d_in[8];
  const float* W_mix           = (const float*)d_in[9];
  const float* W_sc            = (const float*)d_in[10];
  const float* Wp1             = (const float*)d_in[11];
  const float* Wp2             = (const float*)d_in[12];
  const float* Wp3             = (const float*)d_in[13];
  const float* wE1             = (const float*)d_in[14];
  const float* wD1             = (const float*)d_in[15];
  const float* Wh              = (const float*)d_in[16];
  const float* wE2             = (const float*)d_in[17];
  const float* wD2             = (const float*)d_in[18];
  const int*   edge_index      = (const int*)d_in[19];
  const int*   batch           = (const int*)d_in[20];
  float* out = (float*)d_out;

  char* wsp = (char*)d_ws;
  float4* erec   = (float4*)wsp; wsp += sizeof(float4)*(size_t)N_NODES*CAP*2;
  float2* Tab2   = (float2*)wsp; wsp += sizeof(float2)*(size_t)2*TABN*96;
  float*  hg_a   = (float*)wsp;  wsp += sizeof(float)*(size_t)N_NODES*288;
  float*  hg_b   = (float*)wsp;  wsp += sizeof(float)*(size_t)N_NODES*288;
  int* cursor    = (int*)wsp;    wsp += sizeof(int)*N_NODES;
  int* species   = (int*)wsp;    wsp += sizeof(int)*N_NODES;

  hipMemsetAsync(d_out, 0, 64*sizeof(float), stream);
  hipMemsetAsync(cursor, 0, N_NODES*sizeof(int), stream);
  hipMemsetAsync(hg_a, 0, sizeof(float)*(size_t)N_NODES*288, stream);

  prep_kernel<<<802, 256, 0, stream>>>(positions, edge_index, cursor, erec,
                                       node_attrs, W_embed, species, hg_a,
                                       R0, R1, R2, R3, Tab2);

  for (int i = 0; i < 2; i++){
    const float* hin  = (i == 0) ? hg_a : hg_b;
    float*       hout = (i == 0) ? hg_b : hg_a;
    node_kernel<<<N_NODES/NPB, 512, 0, stream>>>(Tab2 + (size_t)i*TABN*96, erec,
                                               cursor, hin, hout,
                                               W_mix + i*3*C*C, W_sc + i*3*C*C,
                                               Wp1 + i*Zn*C, Wp2 + i*Zn*C, Wp3 + i*Zn*C,
                                               species, batch,
                                               atomic_energies, charges, positions,
                                               wE1, (i == 0) ? wD1 : wD2,
                                               Wh, wE2, i, out);
  }
}

// Round 11
// 211.313 us; speedup vs baseline: 1.4872x; 1.2411x over previous
//
#include <hip/hip_runtime.h>
#include <math.h>

#define N_NODES 8192
#define N_EDGES 131072
#define C 32
#define Zn 10
#define NG 16
#define NB 8
#define H 64
#define TABN 4096
#define PPB 32     // table points per block
#define XS 73      // table activation LDS stride
#define NPB 8      // nodes per node_kernel block (1 wave per node)
#define CAP 64     // bucket capacity per node
#define SL 48      // max edges processed per node (Poisson(10): P(>48)~1e-18)

__device__ __forceinline__ float silu_f(float v){ return v / (1.0f + __expf(-v)); }

// ================================================================ prep (fused):
// blocks [0,258): radial MLP tables (FIRST - longest job, 1 blk/CU territory)
// blocks [258,770): edge filter + bucket snd write (4B scatter only)
// blocks [770,802): species + full h0 row init (incl zero padding)
__global__ __launch_bounds__(256)
void prep_kernel(const float* __restrict__ pos, const int* __restrict__ ei,
                 int* __restrict__ cursor, int* __restrict__ bucket,
                 const float* __restrict__ na, const float* __restrict__ Wemb,
                 int* __restrict__ species, float* __restrict__ hg,
                 const float* __restrict__ R0g, const float* __restrict__ R1g,
                 const float* __restrict__ R2g, const float* __restrict__ R3g,
                 float2* __restrict__ Tab2){
  __shared__ float xsh[PPB*XS];
  int b = blockIdx.x;
  int tid = threadIdx.x;

  if (b >= 258){
    if (b < 770){
      int e = (b-258)*256 + tid;
      int snd = ei[e], rcv = ei[N_EDGES + e];
      float px = pos[rcv*3+0]-pos[snd*3+0];
      float py = pos[rcv*3+1]-pos[snd*3+1];
      float pz = pos[rcv*3+2]-pos[snd*3+2];
      float r2 = px*px+py*py+pz*pz;
      if (r2 < 25.0f){
        int slot = atomicAdd(cursor + rcv, 1);
        if (slot < CAP) bucket[rcv*CAP + slot] = snd;
      }
    } else {
      int n = (b-770)*256 + tid;
      int spec = 0;
      #pragma unroll
      for (int z = 1; z < Zn; z++) if (na[n*Zn+z] > 0.5f) spec = z;
      species[n] = spec;
      float4* hrow = (float4*)(hg + (size_t)n*288);
      const float4* wrow = (const float4*)(Wemb + spec*C);
      #pragma unroll
      for (int q = 0; q < 8; q++) hrow[q] = wrow[q];
      float4 z4 = make_float4(0.f,0.f,0.f,0.f);
      #pragma unroll
      for (int q = 8; q < 72; q++) hrow[q] = z4;
    }
    return;
  }

  // ---- table part
  int tb = b;
  const int nb = (TABN + PPB)/PPB;   // 129
  int half = tb / nb;
  int blk  = tb - half*nb;
  const float* R0i = R0g + half*NB*H;
  const float* R1i = R1g + half*H*H;
  const float* R2i = R2g + half*H*H;
  const float* R3i = R3g + half*H*96;
  float2* TabH = Tab2 + (size_t)half*((size_t)TABN*96);

  int pl = tid >> 3, jt = tid & 7;
  int i = blk*PPB + pl;
  float r = (i == 0) ? 1e-6f : (float)i * (5.0f/TABN);
  {
    float xr = r*0.2f;
    float env = 0.f;
    if (xr < 1.0f){
      float x2 = xr*xr, x5 = x2*x2*xr;
      env = 1.f - 21.f*x5 + 35.f*x5*xr - 15.f*x5*x2;
    }
    float sc = 0.6324555320336759f / r * env;
    xsh[pl*XS + jt] = sc * sinf((float)(jt+1)*0.6283185307179586f*r);
  }
  __syncthreads();

  float acc[12];
  #pragma unroll
  for (int j = 0; j < 8; j++) acc[j] = 0.f;
  #pragma unroll
  for (int k = 0; k < 8; k++){
    float xk = xsh[pl*XS + k];
    const float4* w4 = (const float4*)(R0i + k*H + jt*8);
    float4 wa = w4[0], wb = w4[1];
    acc[0]=fmaf(xk,wa.x,acc[0]); acc[1]=fmaf(xk,wa.y,acc[1]);
    acc[2]=fmaf(xk,wa.z,acc[2]); acc[3]=fmaf(xk,wa.w,acc[3]);
    acc[4]=fmaf(xk,wb.x,acc[4]); acc[5]=fmaf(xk,wb.y,acc[5]);
    acc[6]=fmaf(xk,wb.z,acc[6]); acc[7]=fmaf(xk,wb.w,acc[7]);
  }
  __syncthreads();
  #pragma unroll
  for (int j = 0; j < 8; j++) xsh[pl*XS + jt*8 + j] = silu_f(acc[j]);
  __syncthreads();

  const float* Wl[2] = {R1i, R2i};
  #pragma unroll
  for (int L = 0; L < 2; L++){
    const float* W = Wl[L];
    #pragma unroll
    for (int j = 0; j < 8; j++) acc[j] = 0.f;
    #pragma unroll 4
    for (int k = 0; k < H; k++){
      float xk = xsh[pl*XS + k];
      const float4* w4 = (const float4*)(W + k*H + jt*8);
      float4 wa = w4[0], wb = w4[1];
      acc[0]=fmaf(xk,wa.x,acc[0]); acc[1]=fmaf(xk,wa.y,acc[1]);
      acc[2]=fmaf(xk,wa.z,acc[2]); acc[3]=fmaf(xk,wa.w,acc[3]);
      acc[4]=fmaf(xk,wb.x,acc[4]); acc[5]=fmaf(xk,wb.y,acc[5]);
      acc[6]=fmaf(xk,wb.z,acc[6]); acc[7]=fmaf(xk,wb.w,acc[7]);
    }
    __syncthreads();
    #pragma unroll
    for (int j = 0; j < 8; j++) xsh[pl*XS + jt*8 + j] = silu_f(acc[j]);
    __syncthreads();
  }

  #pragma unroll
  for (int j = 0; j < 12; j++) acc[j] = 0.f;
  #pragma unroll 4
  for (int k = 0; k < H; k++){
    float xk = xsh[pl*XS + k];
    const float4* w4 = (const float4*)(R3i + k*96 + jt*12);
    float4 wa = w4[0], wb = w4[1], wc = w4[2];
    acc[0]=fmaf(xk,wa.x,acc[0]);  acc[1]=fmaf(xk,wa.y,acc[1]);
    acc[2]=fmaf(xk,wa.z,acc[2]);  acc[3]=fmaf(xk,wa.w,acc[3]);
    acc[4]=fmaf(xk,wb.x,acc[4]);  acc[5]=fmaf(xk,wb.y,acc[5]);
    acc[6]=fmaf(xk,wb.z,acc[6]);  acc[7]=fmaf(xk,wb.w,acc[7]);
    acc[8]=fmaf(xk,wc.x,acc[8]);  acc[9]=fmaf(xk,wc.y,acc[9]);
    acc[10]=fmaf(xk,wc.z,acc[10]); acc[11]=fmaf(xk,wc.w,acc[11]);
  }
  if (i <= TABN){
    int cb = jt*12;
    #pragma unroll
    for (int j = 0; j < 12; j++){
      int c = cb + j;
      float val = acc[j];
      if (i < TABN) TabH[(size_t)i*96 + c].x = val;      // lerp lower endpoint
      if (i > 0)    TabH[(size_t)(i-1)*96 + c].y = val;  // lerp upper endpoint
    }
  }
}

// ================================================================ node:
// lane-parallel edge preamble -> dependency-free gather loop -> slot-wave mix
// -> gate -> readout.  1 wave per node, NPB=8.
__global__ __launch_bounds__(512)
void node_kernel(const float2* __restrict__ Tab2, const int* __restrict__ bucket,
                 const int* __restrict__ deg,
                 const float* __restrict__ hg_in, float* __restrict__ hg_out,
                 const float* __restrict__ Wm_g, const float* __restrict__ Ws_g,
                 const float* __restrict__ Wp1, const float* __restrict__ Wp2,
                 const float* __restrict__ Wp3,
                 const int* __restrict__ species, const int* __restrict__ batch,
                 const float* __restrict__ ae, const float* __restrict__ charges,
                 const float* __restrict__ pos,
                 const float* __restrict__ wEv, const float* __restrict__ wDv,
                 const float* __restrict__ Whg, const float* __restrict__ wE2g,
                 int iter, float* __restrict__ out){
  __shared__ float WmT[3*32*34];      // [l][d][c], stride 34
  __shared__ float WsT[3*32*34];
  __shared__ float abuf[NPB][288];    // A (gather) -> A-mixed -> h_new
  __shared__ float sbuf[NPB][288];    // sc
  __shared__ float estage[NPB][SL][6];// per-edge {x,y,z,u,snd}
  __shared__ float glds[NG][4];
  int tid = threadIdx.x;
  for (int t = tid; t < 3072; t += 512){
    int l = t >> 10, rem = t & 1023, c = rem >> 5, d = rem & 31;
    WmT[(l*32+d)*34 + c] = Wm_g[t];
    WsT[(l*32+d)*34 + c] = Ws_g[t];
  }
  if (tid < NG*4) glds[tid>>2][tid&3] = 0.f;
  int w = tid >> 6, lane = tid & 63;
  int c31 = lane & 31;
  bool hi = lane >= 32;
  int ng0 = blockIdx.x*NPB;
  int n = ng0 + w;

  // ---- lane-parallel preamble: stage all edge params (no dependent chains later)
  int cnt = deg[n]; if (cnt > SL) cnt = SL;
  if (lane < cnt){
    int snd = bucket[n*CAP + lane];
    float px = pos[n*3+0] - pos[snd*3+0];
    float py = pos[n*3+1] - pos[snd*3+1];
    float pz = pos[n*3+2] - pos[snd*3+2];
    float r = sqrtf(px*px+py*py+pz*pz + 1e-12f);
    float inv = 1.0f/r;
    float* es = &estage[w][lane][0];
    es[0] = px*inv; es[1] = py*inv; es[2] = pz*inv;
    es[3] = r * (TABN/5.0f);
    es[4] = __int_as_float(snd);
  }

  // ---- gather: only independent loads per edge (3 table + 1 hs)
  const float s3 = 1.7320508075688772f;
  const float s5 = 2.23606797749979f;
  const float s15 = 3.872983346207417f;
  int colA = (hi ? 32 : 0) + c31;    // s=0: m0(l0) / m1(l1)
  int colB = 32 + c31;               // s=1: m2,m3 -> l=1
  int colC = 64 + c31;               // s=2,3,4: l=2
  float acc0=0.f, acc1=0.f, acc2=0.f, acc3=0.f, acc4=0.f;
  #pragma unroll 4
  for (int j = 0; j < cnt; j++){
    const float* es = &estage[w][j][0];
    float x = es[0], y = es[1], z = es[2], u = es[3];
    int snd = __float_as_int(es[4]);
    int i0 = (int)u;
    if (i0 > TABN-1) i0 = TABN-1;
    float f = u - (float)i0;
    const float2* T2 = Tab2 + (size_t)i0*96;
    float hs = hg_in[(size_t)snd*288 + c31];
    float2 ta = T2[colA];
    float2 tb = T2[colB];
    float2 tc = T2[colC];
    float wv0 = fmaf(ta.y - ta.x, f, ta.x) * hs;
    float wv1 = fmaf(tb.y - tb.x, f, tb.x) * hs;
    float wv2 = fmaf(tc.y - tc.x, f, tc.x) * hs;
    float Ys0 = hi ? s3*x : 1.0f;
    float Ys1 = s3 * (hi ? z : y);
    float Ys2 = s15 * (hi ? y*z : x*y);
    float Ys3 = hi ? s15*x*z : 0.5f*s5*(3.f*z*z - 1.f);
    float Ys4 = 0.5f*s15*(x*x - y*y);
    acc0 = fmaf(wv0, Ys0, acc0);
    acc1 = fmaf(wv1, Ys1, acc1);
    acc2 = fmaf(wv2, Ys2, acc2);
    acc3 = fmaf(wv2, Ys3, acc3);
    acc4 = fmaf(wv2, Ys4, acc4);
  }
  abuf[w][lane]       = acc0 * (1.0f/16.0f);
  abuf[w][lane + 64]  = acc1 * (1.0f/16.0f);
  abuf[w][lane + 128] = acc2 * (1.0f/16.0f);
  abuf[w][lane + 192] = acc3 * (1.0f/16.0f);
  if (!hi) abuf[w][lane + 256] = acc4 * (1.0f/16.0f);
  __syncthreads();

  // ---- mix: waves 0..4 each own slot w across the 8 nodes
  float a2[NPB], scv[NPB];
  int idx0 = w*64 + lane;
  bool actm = (w < 5) && (idx0 < 288);
  if (w < 5){
    int m = idx0 >> 5; if (m > 8) m = 8;
    int l = (m >= 4) ? 2 : ((m >= 1) ? 1 : 0);
    const float* wmB = WmT + (l*32 + c31)*34;
    const float* wsB = WsT + (l*32 + c31)*34;
    #pragma unroll
    for (int n2 = 0; n2 < NPB; n2++){ a2[n2] = 0.f; scv[n2] = 0.f; }
    #pragma unroll
    for (int q = 0; q < 8; q++){
      float2 wa0 = *(const float2*)(wmB + 4*q);
      float2 wa1 = *(const float2*)(wmB + 4*q + 2);
      float2 sa0 = *(const float2*)(wsB + 4*q);
      float2 sa1 = *(const float2*)(wsB + 4*q + 2);
      #pragma unroll
      for (int n2 = 0; n2 < NPB; n2++){
        float4 av = *(const float4*)(&abuf[n2][m*32 + 4*q]);
        float4 hv = *(const float4*)(hg_in + (size_t)(ng0+n2)*288 + m*32 + 4*q);
        a2[n2] = fmaf(av.x, wa0.x, a2[n2]); a2[n2] = fmaf(av.y, wa0.y, a2[n2]);
        a2[n2] = fmaf(av.z, wa1.x, a2[n2]); a2[n2] = fmaf(av.w, wa1.y, a2[n2]);
        scv[n2] = fmaf(hv.x, sa0.x, scv[n2]); scv[n2] = fmaf(hv.y, sa0.y, scv[n2]);
        scv[n2] = fmaf(hv.z, sa1.x, scv[n2]); scv[n2] = fmaf(hv.w, sa1.y, scv[n2]);
      }
    }
  }
  __syncthreads();                              // all A reads done
  if (actm){
    #pragma unroll
    for (int n2 = 0; n2 < NPB; n2++){
      abuf[n2][idx0] = a2[n2];
      sbuf[n2][idx0] = scv[n2];
    }
  }
  __syncthreads();

  // ---- gate + h write + readout (wave w = node n)
  int spec = species[n];
  float sval = abuf[w][c31];
  float p1 = Wp1[spec*C+c31], p2 = Wp2[spec*C+c31], p3 = Wp3[spec*C+c31];
  float f = p1 + p2*sval + p3*sval*sval;
  #pragma unroll
  for (int it = 0; it < 5; it++){
    int idx = it*64 + lane;
    if (idx < 288){
      float hn = abuf[w][idx]*f + sbuf[w][idx];
      hg_out[(size_t)n*288 + idx] = hn;
      abuf[w][idx] = hn;
    }
  }

  int g = batch[n];
  float dv0 = 0.f, dv1 = 0.f, dv2 = 0.f, ev = 0.f;
  if (lane < 32){
    dv0 = abuf[w][32+lane]*wDv[lane];
    dv1 = abuf[w][64+lane]*wDv[lane];
    dv2 = abuf[w][96+lane]*wDv[lane];
  }
  if (iter == 0){
    if (lane < 32) ev = abuf[w][lane]*wEv[lane];
  } else {
    if (lane < 16){
      float hid = 0.f;
      #pragma unroll
      for (int c = 0; c < 32; c++) hid = fmaf(abuf[w][c], Whg[c*16+lane], hid);
      hid = silu_f(hid);
      ev = hid * wE2g[lane];
    }
  }
  #pragma unroll
  for (int off = 16; off >= 1; off >>= 1){
    ev  += __shfl_down(ev,  off);
    dv0 += __shfl_down(dv0, off);
    dv1 += __shfl_down(dv1, off);
    dv2 += __shfl_down(dv2, off);
  }
  if (lane == 0){
    if (iter == 0){
      ev += ae[spec];
      float q = charges[n];
      dv0 += q*pos[n*3+0];
      dv1 += q*pos[n*3+1];
      dv2 += q*pos[n*3+2];
    }
    atomicAdd(&glds[g][0], ev);
    atomicAdd(&glds[g][1], dv0);
    atomicAdd(&glds[g][2], dv1);
    atomicAdd(&glds[g][3], dv2);
  }
  __syncthreads();
  if (tid < NG*4){
    float v = glds[tid>>2][tid&3];
    if (v != 0.f) atomicAdd(out + tid, v);
  }
}

// ================================================================ launch
extern "C" void kernel_launch(void* const* d_in, const int* in_sizes, int n_in,
                              void* d_out, int out_size, void* d_ws, size_t ws_size,
                              hipStream_t stream){
  const float* positions       = (const float*)d_in[0];
  const float* node_attrs      = (const float*)d_in[1];
  const float* charges         = (const float*)d_in[2];
  const float* atomic_energies = (const float*)d_in[3];
  const float* W_embed         = (const float*)d_in[4];
  const float* R0              = (const float*)d_in[5];
  const float* R1              = (const float*)d_in[6];
  const float* R2              = (const float*)d_in[7];
  const float* R3              = (const float*)d_in[8];
  const float* W_mix           = (const float*)d_in[9];
  const float* W_sc            = (const float*)d_in[10];
  const float* Wp1             = (const float*)d_in[11];
  const float* Wp2             = (const float*)d_in[12];
  const float* Wp3             = (const float*)d_in[13];
  const float* wE1             = (const float*)d_in[14];
  const float* wD1             = (const float*)d_in[15];
  const float* Wh              = (const float*)d_in[16];
  const float* wE2             = (const float*)d_in[17];
  const float* wD2             = (const float*)d_in[18];
  const int*   edge_index      = (const int*)d_in[19];
  const int*   batch           = (const int*)d_in[20];
  float* out = (float*)d_out;

  char* wsp = (char*)d_ws;
  int*    bucket = (int*)wsp;    wsp += sizeof(int)*(size_t)N_NODES*CAP;
  float2* Tab2   = (float2*)wsp; wsp += sizeof(float2)*(size_t)2*TABN*96;
  float*  hg_a   = (float*)wsp;  wsp += sizeof(float)*(size_t)N_NODES*288;
  float*  hg_b   = (float*)wsp;  wsp += sizeof(float)*(size_t)N_NODES*288;
  int* cursor    = (int*)wsp;    wsp += sizeof(int)*N_NODES;
  int* species   = (int*)wsp;    wsp += sizeof(int)*N_NODES;

  hipMemsetAsync(d_out, 0, 64*sizeof(float), stream);
  hipMemsetAsync(cursor, 0, N_NODES*sizeof(int), stream);

  prep_kernel<<<802, 256, 0, stream>>>(positions, edge_index, cursor, bucket,
                                       node_attrs, W_embed, species, hg_a,
                                       R0, R1, R2, R3, Tab2);

  for (int i = 0; i < 2; i++){
    const float* hin  = (i == 0) ? hg_a : hg_b;
    float*       hout = (i == 0) ? hg_b : hg_a;
    node_kernel<<<N_NODES/NPB, 512, 0, stream>>>(Tab2 + (size_t)i*TABN*96, bucket,
                                               cursor, hin, hout,
                                               W_mix + i*3*C*C, W_sc + i*3*C*C,
                                               Wp1 + i*Zn*C, Wp2 + i*Zn*C, Wp3 + i*Zn*C,
                                               species, batch,
                                               atomic_energies, charges, positions,
                                               wE1, (i == 0) ? wD1 : wD2,
                                               Wh, wE2, i, out);
  }
}

// Round 12
// 206.716 us; speedup vs baseline: 1.5202x; 1.0222x over previous
//
#include <hip/hip_runtime.h>
#include <math.h>

#define N_NODES 8192
#define N_EDGES 131072
#define C 32
#define Zn 10
#define NG 16
#define NB 8
#define H 64
#define TABN 4096
#define PPB 32     // table points per block
#define XS 73      // table activation LDS stride
#define NPB 8      // nodes per node_kernel block (1 wave per node)
#define CAP 64     // bucket capacity per node
#define SL 48      // max edges processed per node

__device__ __forceinline__ float silu_f(float v){ return v / (1.0f + __expf(-v)); }

// ================================================================ prep (fused):
// blocks [0,258): radial MLP tables (longest serial job - dispatched first)
// blocks [258,386): species + coalesced h0 row init (64 nodes/block)
// blocks [386,898): edge filter + bucket snd write (4B scatter only)
__global__ __launch_bounds__(256)
void prep_kernel(const float* __restrict__ pos, const int* __restrict__ ei,
                 int* __restrict__ cursor, int* __restrict__ bucket,
                 const float* __restrict__ na, const float* __restrict__ Wemb,
                 int* __restrict__ species, float* __restrict__ hg,
                 const float* __restrict__ R0g, const float* __restrict__ R1g,
                 const float* __restrict__ R2g, const float* __restrict__ R3g,
                 float2* __restrict__ Tab2, float* __restrict__ out){
  __shared__ float xsh[PPB*XS];
  __shared__ int spec_lds[64];
  int b = blockIdx.x;
  int tid = threadIdx.x;

  if (b >= 258){
    if (b < 386){
      // ---- species + h0 (coalesced)
      int n0 = (b-258)*64;
      if (tid < 64){
        int n = n0 + tid;
        int spec = 0;
        #pragma unroll
        for (int z = 1; z < Zn; z++) if (na[n*Zn+z] > 0.5f) spec = z;
        species[n] = spec;
        spec_lds[tid] = spec;
      }
      if (b == 258 && tid >= 64 && tid < 128) out[tid-64] = 0.f;
      __syncthreads();
      float4* dst = (float4*)(hg + (size_t)n0*288);
      const float4 z4 = make_float4(0.f,0.f,0.f,0.f);
      #pragma unroll
      for (int it = 0; it < 18; it++){
        int f = it*256 + tid;          // [0, 4608)
        int node = f / 72;
        int q = f - node*72;
        float4 v = z4;
        if (q < 8) v = ((const float4*)(Wemb + spec_lds[node]*C))[q];
        dst[f] = v;
      }
    } else {
      // ---- edge filter + bucket
      int e = (b-386)*256 + tid;
      int snd = ei[e], rcv = ei[N_EDGES + e];
      float px = pos[rcv*3+0]-pos[snd*3+0];
      float py = pos[rcv*3+1]-pos[snd*3+1];
      float pz = pos[rcv*3+2]-pos[snd*3+2];
      float r2 = px*px+py*py+pz*pz;
      if (r2 < 25.0f){
        int slot = atomicAdd(cursor + rcv, 1);
        if (slot < CAP) bucket[rcv*CAP + slot] = snd;
      }
    }
    return;
  }

  // ---- table part
  int tb = b;
  const int nb = (TABN + PPB)/PPB;   // 129
  int half = tb / nb;
  int blk  = tb - half*nb;
  const float* R0i = R0g + half*NB*H;
  const float* R1i = R1g + half*H*H;
  const float* R2i = R2g + half*H*H;
  const float* R3i = R3g + half*H*96;
  float2* TabH = Tab2 + (size_t)half*((size_t)TABN*96);

  int pl = tid >> 3, jt = tid & 7;
  int i = blk*PPB + pl;
  float r = (i == 0) ? 1e-6f : (float)i * (5.0f/TABN);
  {
    float xr = r*0.2f;
    float env = 0.f;
    if (xr < 1.0f){
      float x2 = xr*xr, x5 = x2*x2*xr;
      env = 1.f - 21.f*x5 + 35.f*x5*xr - 15.f*x5*x2;
    }
    float sc = 0.6324555320336759f / r * env;
    xsh[pl*XS + jt] = sc * sinf((float)(jt+1)*0.6283185307179586f*r);
  }
  __syncthreads();

  float acc[12];
  #pragma unroll
  for (int j = 0; j < 8; j++) acc[j] = 0.f;
  #pragma unroll
  for (int k = 0; k < 8; k++){
    float xk = xsh[pl*XS + k];
    const float4* w4 = (const float4*)(R0i + k*H + jt*8);
    float4 wa = w4[0], wb = w4[1];
    acc[0]=fmaf(xk,wa.x,acc[0]); acc[1]=fmaf(xk,wa.y,acc[1]);
    acc[2]=fmaf(xk,wa.z,acc[2]); acc[3]=fmaf(xk,wa.w,acc[3]);
    acc[4]=fmaf(xk,wb.x,acc[4]); acc[5]=fmaf(xk,wb.y,acc[5]);
    acc[6]=fmaf(xk,wb.z,acc[6]); acc[7]=fmaf(xk,wb.w,acc[7]);
  }
  __syncthreads();
  #pragma unroll
  for (int j = 0; j < 8; j++) xsh[pl*XS + jt*8 + j] = silu_f(acc[j]);
  __syncthreads();

  const float* Wl[2] = {R1i, R2i};
  #pragma unroll
  for (int L = 0; L < 2; L++){
    const float* W = Wl[L];
    #pragma unroll
    for (int j = 0; j < 8; j++) acc[j] = 0.f;
    #pragma unroll 8
    for (int k = 0; k < H; k++){
      float xk = xsh[pl*XS + k];
      const float4* w4 = (const float4*)(W + k*H + jt*8);
      float4 wa = w4[0], wb = w4[1];
      acc[0]=fmaf(xk,wa.x,acc[0]); acc[1]=fmaf(xk,wa.y,acc[1]);
      acc[2]=fmaf(xk,wa.z,acc[2]); acc[3]=fmaf(xk,wa.w,acc[3]);
      acc[4]=fmaf(xk,wb.x,acc[4]); acc[5]=fmaf(xk,wb.y,acc[5]);
      acc[6]=fmaf(xk,wb.z,acc[6]); acc[7]=fmaf(xk,wb.w,acc[7]);
    }
    __syncthreads();
    #pragma unroll
    for (int j = 0; j < 8; j++) xsh[pl*XS + jt*8 + j] = silu_f(acc[j]);
    __syncthreads();
  }

  #pragma unroll
  for (int j = 0; j < 12; j++) acc[j] = 0.f;
  #pragma unroll 8
  for (int k = 0; k < H; k++){
    float xk = xsh[pl*XS + k];
    const float4* w4 = (const float4*)(R3i + k*96 + jt*12);
    float4 wa = w4[0], wb = w4[1], wc = w4[2];
    acc[0]=fmaf(xk,wa.x,acc[0]);  acc[1]=fmaf(xk,wa.y,acc[1]);
    acc[2]=fmaf(xk,wa.z,acc[2]);  acc[3]=fmaf(xk,wa.w,acc[3]);
    acc[4]=fmaf(xk,wb.x,acc[4]);  acc[5]=fmaf(xk,wb.y,acc[5]);
    acc[6]=fmaf(xk,wb.z,acc[6]);  acc[7]=fmaf(xk,wb.w,acc[7]);
    acc[8]=fmaf(xk,wc.x,acc[8]);  acc[9]=fmaf(xk,wc.y,acc[9]);
    acc[10]=fmaf(xk,wc.z,acc[10]); acc[11]=fmaf(xk,wc.w,acc[11]);
  }
  if (i <= TABN){
    int cb = jt*12;
    #pragma unroll
    for (int j = 0; j < 12; j++){
      int c = cb + j;
      float val = acc[j];
      if (i < TABN) TabH[(size_t)i*96 + c].x = val;      // lerp lower endpoint
      if (i > 0)    TabH[(size_t)(i-1)*96 + c].y = val;  // lerp upper endpoint
    }
  }
}

// ================================================================ node:
// lane-parallel preamble -> dependency-free gather -> global-weight mix
// -> gate -> readout.  1 wave per node, NPB=8, LDS ~19 KB (estage aliases sbuf).
__global__ __launch_bounds__(512)
void node_kernel(const float2* __restrict__ Tab2, const int* __restrict__ bucket,
                 const int* __restrict__ deg,
                 const float* __restrict__ hg_in, float* __restrict__ hg_out,
                 const float* __restrict__ Wm_g, const float* __restrict__ Ws_g,
                 const float* __restrict__ Wp1, const float* __restrict__ Wp2,
                 const float* __restrict__ Wp3,
                 const int* __restrict__ species, const int* __restrict__ batch,
                 const float* __restrict__ ae, const float* __restrict__ charges,
                 const float* __restrict__ pos,
                 const float* __restrict__ wEv, const float* __restrict__ wDv,
                 const float* __restrict__ Whg, const float* __restrict__ wE2g,
                 int iter, float* __restrict__ out){
  __shared__ float abuf[NPB][288];    // A (gather) -> A-mixed -> h_new
  __shared__ float sbuf[NPB][288];    // estage during gather -> sc after mix
  __shared__ float glds[NG][4];
  float* estage = &sbuf[0][0];        // NPB*SL*6 = 2304 = NPB*288, exact alias
  int tid = threadIdx.x;
  if (tid < NG*4) glds[tid>>2][tid&3] = 0.f;
  int w = tid >> 6, lane = tid & 63;
  int c31 = lane & 31;
  bool hi = lane >= 32;
  int ng0 = blockIdx.x*NPB;
  int n = ng0 + w;

  // ---- lane-parallel preamble: stage all edge params
  int cnt = deg[n]; if (cnt > SL) cnt = SL;
  if (lane < cnt){
    int snd = bucket[n*CAP + lane];
    float px = pos[n*3+0] - pos[snd*3+0];
    float py = pos[n*3+1] - pos[snd*3+1];
    float pz = pos[n*3+2] - pos[snd*3+2];
    float r = sqrtf(px*px+py*py+pz*pz + 1e-12f);
    float inv = 1.0f/r;
    float* es = estage + (w*SL + lane)*6;
    es[0] = px*inv; es[1] = py*inv; es[2] = pz*inv;
    es[3] = r * (TABN/5.0f);
    es[4] = __int_as_float(snd);
  }

  // ---- gather: only independent loads per edge (3 table + 1 hs)
  const float s3 = 1.7320508075688772f;
  const float s5 = 2.23606797749979f;
  const float s15 = 3.872983346207417f;
  int colA = (hi ? 32 : 0) + c31;    // s=0: m0(l0) / m1(l1)
  int colB = 32 + c31;               // s=1: m2,m3 -> l=1
  int colC = 64 + c31;               // s=2,3,4: l=2
  float acc0=0.f, acc1=0.f, acc2=0.f, acc3=0.f, acc4=0.f;
  #pragma unroll 4
  for (int j = 0; j < cnt; j++){
    const float* es = estage + (w*SL + j)*6;
    float x = es[0], y = es[1], z = es[2], u = es[3];
    int snd = __float_as_int(es[4]);
    int i0 = (int)u;
    if (i0 > TABN-1) i0 = TABN-1;
    float f = u - (float)i0;
    const float2* T2 = Tab2 + (size_t)i0*96;
    float hs = hg_in[(size_t)snd*288 + c31];
    float2 ta = T2[colA];
    float2 tb = T2[colB];
    float2 tc = T2[colC];
    float wv0 = fmaf(ta.y - ta.x, f, ta.x) * hs;
    float wv1 = fmaf(tb.y - tb.x, f, tb.x) * hs;
    float wv2 = fmaf(tc.y - tc.x, f, tc.x) * hs;
    float Ys0 = hi ? s3*x : 1.0f;
    float Ys1 = s3 * (hi ? z : y);
    float Ys2 = s15 * (hi ? y*z : x*y);
    float Ys3 = hi ? s15*x*z : 0.5f*s5*(3.f*z*z - 1.f);
    float Ys4 = 0.5f*s15*(x*x - y*y);
    acc0 = fmaf(wv0, Ys0, acc0);
    acc1 = fmaf(wv1, Ys1, acc1);
    acc2 = fmaf(wv2, Ys2, acc2);
    acc3 = fmaf(wv2, Ys3, acc3);
    acc4 = fmaf(wv2, Ys4, acc4);
  }
  __syncthreads();                    // estage fully consumed (it aliases sbuf)
  abuf[w][lane]       = acc0 * (1.0f/16.0f);
  abuf[w][lane + 64]  = acc1 * (1.0f/16.0f);
  abuf[w][lane + 128] = acc2 * (1.0f/16.0f);
  abuf[w][lane + 192] = acc3 * (1.0f/16.0f);
  if (!hi) abuf[w][lane + 256] = acc4 * (1.0f/16.0f);
  __syncthreads();

  // ---- mix: waves 0..4 each own slot w across the 8 nodes; weights direct
  // from global (coalesced: W[l*1024 + c*32 + c31] across lanes), L1-hot.
  float a2[NPB], scv[NPB];
  int idx0 = w*64 + lane;
  bool actm = (w < 5) && (idx0 < 288);
  if (w < 5){
    int m = idx0 >> 5; if (m > 8) m = 8;
    int l = (m >= 4) ? 2 : ((m >= 1) ? 1 : 0);
    const float* wmB = Wm_g + l*1024 + c31;
    const float* wsB = Ws_g + l*1024 + c31;
    #pragma unroll
    for (int n2 = 0; n2 < NPB; n2++){ a2[n2] = 0.f; scv[n2] = 0.f; }
    #pragma unroll
    for (int q = 0; q < 8; q++){
      float w0 = wmB[(4*q+0)*32], w1 = wmB[(4*q+1)*32];
      float w2 = wmB[(4*q+2)*32], w3 = wmB[(4*q+3)*32];
      float t0 = wsB[(4*q+0)*32], t1 = wsB[(4*q+1)*32];
      float t2 = wsB[(4*q+2)*32], t3 = wsB[(4*q+3)*32];
      #pragma unroll
      for (int n2 = 0; n2 < NPB; n2++){
        float4 av = *(const float4*)(&abuf[n2][m*32 + 4*q]);
        float4 hv = *(const float4*)(hg_in + (size_t)(ng0+n2)*288 + m*32 + 4*q);
        a2[n2] = fmaf(av.x, w0, a2[n2]); a2[n2] = fmaf(av.y, w1, a2[n2]);
        a2[n2] = fmaf(av.z, w2, a2[n2]); a2[n2] = fmaf(av.w, w3, a2[n2]);
        scv[n2] = fmaf(hv.x, t0, scv[n2]); scv[n2] = fmaf(hv.y, t1, scv[n2]);
        scv[n2] = fmaf(hv.z, t2, scv[n2]); scv[n2] = fmaf(hv.w, t3, scv[n2]);
      }
    }
  }
  __syncthreads();                              // all A reads done
  if (actm){
    #pragma unroll
    for (int n2 = 0; n2 < NPB; n2++){
      abuf[n2][idx0] = a2[n2];
      sbuf[n2][idx0] = scv[n2];
    }
  }
  __syncthreads();

  // ---- gate + h write + readout (wave w = node n)
  int spec = species[n];
  float sval = abuf[w][c31];
  float p1 = Wp1[spec*C+c31], p2 = Wp2[spec*C+c31], p3 = Wp3[spec*C+c31];
  float f = p1 + p2*sval + p3*sval*sval;
  #pragma unroll
  for (int it = 0; it < 5; it++){
    int idx = it*64 + lane;
    if (idx < 288){
      float hn = abuf[w][idx]*f + sbuf[w][idx];
      hg_out[(size_t)n*288 + idx] = hn;
      abuf[w][idx] = hn;
    }
  }

  int g = batch[n];
  float dv0 = 0.f, dv1 = 0.f, dv2 = 0.f, ev = 0.f;
  if (lane < 32){
    dv0 = abuf[w][32+lane]*wDv[lane];
    dv1 = abuf[w][64+lane]*wDv[lane];
    dv2 = abuf[w][96+lane]*wDv[lane];
  }
  if (iter == 0){
    if (lane < 32) ev = abuf[w][lane]*wEv[lane];
  } else {
    if (lane < 16){
      float hid = 0.f;
      #pragma unroll
      for (int c = 0; c < 32; c++) hid = fmaf(abuf[w][c], Whg[c*16+lane], hid);
      hid = silu_f(hid);
      ev = hid * wE2g[lane];
    }
  }
  #pragma unroll
  for (int off = 16; off >= 1; off >>= 1){
    ev  += __shfl_down(ev,  off);
    dv0 += __shfl_down(dv0, off);
    dv1 += __shfl_down(dv1, off);
    dv2 += __shfl_down(dv2, off);
  }
  if (lane == 0){
    if (iter == 0){
      ev += ae[spec];
      float q = charges[n];
      dv0 += q*pos[n*3+0];
      dv1 += q*pos[n*3+1];
      dv2 += q*pos[n*3+2];
    }
    atomicAdd(&glds[g][0], ev);
    atomicAdd(&glds[g][1], dv0);
    atomicAdd(&glds[g][2], dv1);
    atomicAdd(&glds[g][3], dv2);
  }
  __syncthreads();
  if (tid < NG*4){
    float v = glds[tid>>2][tid&3];
    if (v != 0.f) atomicAdd(out + tid, v);
  }
}

// ================================================================ launch
extern "C" void kernel_launch(void* const* d_in, const int* in_sizes, int n_in,
                              void* d_out, int out_size, void* d_ws, size_t ws_size,
                              hipStream_t stream){
  const float* positions       = (const float*)d_in[0];
  const float* node_attrs      = (const float*)d_in[1];
  const float* charges         = (const float*)d_in[2];
  const float* atomic_energies = (const float*)d_in[3];
  const float* W_embed         = (const float*)d_in[4];
  const float* R0              = (const float*)d_in[5];
  const float* R1              = (const float*)d_in[6];
  const float* R2              = (const float*)d_in[7];
  const float* R3              = (const float*)d_in[8];
  const float* W_mix           = (const float*)d_in[9];
  const float* W_sc            = (const float*)d_in[10];
  const float* Wp1             = (const float*)d_in[11];
  const float* Wp2             = (const float*)d_in[12];
  const float* Wp3             = (const float*)d_in[13];
  const float* wE1             = (const float*)d_in[14];
  const float* wD1             = (const float*)d_in[15];
  const float* Wh              = (const float*)d_in[16];
  const float* wE2             = (const float*)d_in[17];
  const float* wD2             = (const float*)d_in[18];
  const int*   edge_index      = (const int*)d_in[19];
  const int*   batch           = (const int*)d_in[20];
  float* out = (float*)d_out;

  char* wsp = (char*)d_ws;
  int*    bucket = (int*)wsp;    wsp += sizeof(int)*(size_t)N_NODES*CAP;
  float2* Tab2   = (float2*)wsp; wsp += sizeof(float2)*(size_t)2*TABN*96;
  float*  hg_a   = (float*)wsp;  wsp += sizeof(float)*(size_t)N_NODES*288;
  float*  hg_b   = (float*)wsp;  wsp += sizeof(float)*(size_t)N_NODES*288;
  int* cursor    = (int*)wsp;    wsp += sizeof(int)*N_NODES;
  int* species   = (int*)wsp;    wsp += sizeof(int)*N_NODES;

  hipMemsetAsync(cursor, 0, N_NODES*sizeof(int), stream);

  prep_kernel<<<898, 256, 0, stream>>>(positions, edge_index, cursor, bucket,
                                       node_attrs, W_embed, species, hg_a,
                                       R0, R1, R2, R3, Tab2, out);

  for (int i = 0; i < 2; i++){
    const float* hin  = (i == 0) ? hg_a : hg_b;
    float*       hout = (i == 0) ? hg_b : hg_a;
    node_kernel<<<N_NODES/NPB, 512, 0, stream>>>(Tab2 + (size_t)i*TABN*96, bucket,
                                               cursor, hin, hout,
                                               W_mix + i*3*C*C, W_sc + i*3*C*C,
                                               Wp1 + i*Zn*C, Wp2 + i*Zn*C, Wp3 + i*Zn*C,
                                               species, batch,
                                               atomic_energies, charges, positions,
                                               wE1, (i == 0) ? wD1 : wD2,
                                               Wh, wE2, i, out);
  }
}